// Round 1
// baseline (996.335 us; speedup 1.0000x reference)
//
#include <hip/hip_runtime.h>
#include <stdint.h>

// Problem constants
#define KCOMP 65536
#define DDIM  256
#define ODIM  256
#define BROWS 1024
#define NBLK  512            // main grid: KCOMP / 128 comps per block
#define LOG2PI_TERM 235.2482645f   // 128 * ln(2*pi) = 0.5*D*ln(2pi)

typedef float f32x4 __attribute__((ext_vector_type(4)));
typedef __bf16 bf16x8 __attribute__((ext_vector_type(8)));
typedef unsigned int u32;
typedef unsigned long long u64;
typedef unsigned short u16;

typedef __attribute__((address_space(1))) const u32 gconst_u32;
typedef __attribute__((address_space(3))) u32 lds_u32;

// round-to-nearest-even f32 -> bf16 bits
__device__ __forceinline__ u16 f2bf(float f) {
  u32 b = __float_as_uint(f);
  b += 0x7FFFu + ((b >> 16) & 1u);
  return (u16)(b >> 16);
}

// ws layout (bytes). Total need: ~82 MB.
#define WS_A     0                          // 1 MB   A feat frag-linear [64 m16][16 kc][64 lane][16B]
#define WS_W     (1u << 20)                 // 64 MB  W frag-linear [4096 grp][16 kc][64 lane][16B]
#define WS_CONST (WS_W + (64u << 20))       // 256 KB const per comp
#define WS_CVAL  (WS_CONST + (256u << 10))  // 8 MB   cand values [1024][512][4]
#define WS_CIDX  (WS_CVAL + (8u << 20))     // 8 MB   cand indices

// ---------------------------------------------------------------------------
// Kernel 1: A features. A[m][kappa]: kappa=2d -> x_d^2 ; kappa=2d+1 -> -2 x_d.
// Stored frag-linear: lane l of (m16 t, kchunk cc) holds m=t*16+(l&15),
// kappa = cc*32 + (l>>4)*8 + j, j=0..7 (matches mfma A-operand layout).
__global__ void prep_A(const float* __restrict__ x, u16* __restrict__ A) {
  int l = threadIdx.x & 63;
  int wv = threadIdx.x >> 6;
  int t = blockIdx.x;                 // 0..63
  int row = t * 16 + (l & 15);
  for (int u = 0; u < 4; ++u) {
    int cc = wv * 4 + u;              // 0..15
    int d0 = cc * 16 + ((l >> 4) << 2);
    float4 xv = *(const float4*)(x + (size_t)row * DDIM + d0);
    float xs[4] = {xv.x, xv.y, xv.z, xv.w};
    uint4 v;
    u32 wds[4];
    for (int e = 0; e < 4; ++e)
      wds[e] = (u32)f2bf(xs[e] * xs[e]) | ((u32)f2bf(-2.0f * xs[e]) << 16);
    v.x = wds[0]; v.y = wds[1]; v.z = wds[2]; v.w = wds[3];
    *(uint4*)(A + ((size_t)(t * 16 + cc) * 64 + l) * 8) = v;
  }
}

// ---------------------------------------------------------------------------
// Kernel 2: W weights + per-comp constant.
// W[n][kappa]: kappa=2d -> inv_var ; kappa=2d+1 -> mean*inv_var.
// Frag-linear per 16-comp group g: lane lt of (g, cc) holds n = g*16+(lt&15),
// kappa = cc*32 + (lt>>4)*8 + j (mfma B-operand layout).
// const[n] = -0.5*sum(m^2*iv) - sum(log s) - 128*ln(2pi)
__global__ void prep_W(const float* __restrict__ mean, const float* __restrict__ stdd,
                       u16* __restrict__ W, float* __restrict__ ck) {
  int l = threadIdx.x & 63;
  int wv = threadIdx.x >> 6;
  int g = blockIdx.x * 4 + wv;        // 0..4095
  for (int p = 0; p < 16; ++p) {
    int comp = g * 16 + p;
    float4 m4 = *(const float4*)(mean + (size_t)comp * DDIM + l * 4);
    float4 s4 = *(const float4*)(stdd + (size_t)comp * DDIM + l * 4);
    float ms[4] = {m4.x, m4.y, m4.z, m4.w};
    float ss[4] = {s4.x, s4.y, s4.z, s4.w};
    u32 wds[4];
    float gsum = 0.f;
    for (int e = 0; e < 4; ++e) {
      float iv = 1.0f / (ss[e] * ss[e]);
      float miv = ms[e] * iv;
      wds[e] = (u32)f2bf(iv) | ((u32)f2bf(miv) << 16);
      gsum += -0.5f * ms[e] * miv - logf(ss[e]);
    }
    for (int d = 1; d < 64; d <<= 1) gsum += __shfl_xor(gsum, d);
    if (l == 0) ck[comp] = gsum - LOG2PI_TERM;
    // lane l produced kappa=8l..8l+7 of comp p -> frag slot cc=l>>2, lane (l&3)*16+p
    uint4 v; v.x = wds[0]; v.y = wds[1]; v.z = wds[2]; v.w = wds[3];
    size_t slot = (size_t)(g * 16 + (l >> 2)) * 64 + (size_t)((l & 3) * 16 + p);
    *(uint4*)(W + slot * 8) = v;
  }
}

// ---------------------------------------------------------------------------
// Kernel 3: main GEMM. Grid 512 blocks x 512 thr (8 waves).
// Block owns 128 comps (8 waves x 16); each wave keeps its full W slice
// (16 frags = 64 VGPRs) in registers. A streams via global_load_lds, dbuf.
// Epilogue: per-row top-4 over the block's 128 comps -> cand arrays.
__global__ __launch_bounds__(512, 2)
void main_gemm(const u16* __restrict__ A_ws, const u16* __restrict__ W_ws,
               const float* __restrict__ ck, float* __restrict__ cval,
               int* __restrict__ cidx) {
  __shared__ u16 Ash[2][16][512];      // 2 x 16 cells x (64 lanes x 8 bf16) = 32 KB
  __shared__ float ssc[32][133];       // score sub-batch, padded
  __shared__ u64 ssel[32][4][4];       // per-row per-quarter top-4 (packed key)
  int tid = threadIdx.x, l = tid & 63, w = tid >> 6;
  int g = blockIdx.x * 8 + w;          // 16-comp group of this wave

  bf16x8 wf[16];
#pragma unroll
  for (int cc = 0; cc < 16; ++cc)
    wf[cc] = *(const bf16x8*)(W_ws + ((size_t)(g * 16 + cc) * 64 + l) * 8);
  float myc = ck[g * 16 + (l & 15)];

  for (int mc = 0; mc < 8; ++mc) {
    f32x4 acc[8];
#pragma unroll
    for (int t = 0; t < 8; ++t) acc[t] = (f32x4){0.f, 0.f, 0.f, 0.f};

    // stage(s): wave w stages its m16 tile (mc*8+w), kc = s*2 and s*2+1
#define STAGE(S, BUF)                                                          \
    {                                                                          \
      _Pragma("unroll")                                                        \
      for (int k2 = 0; k2 < 2; ++k2) {                                         \
        const u16* gsrc = A_ws +                                               \
          ((size_t)(mc * 8 + w) * 16 + (S) * 2 + k2) * 512 + (size_t)l * 8;    \
        __builtin_amdgcn_global_load_lds((gconst_u32*)gsrc,                    \
            (lds_u32*)&Ash[BUF][w * 2 + k2][0], 16, 0, 0);                     \
      }                                                                        \
    }

    STAGE(0, 0)
    for (int s = 0; s < 8; ++s) {
      __syncthreads();                     // staged buf visible to all waves
      if (s < 7) STAGE(s + 1, (s + 1) & 1)
      int buf = s & 1;
#pragma unroll
      for (int t = 0; t < 8; ++t)
#pragma unroll
        for (int k2 = 0; k2 < 2; ++k2) {
          bf16x8 a = *(const bf16x8*)(&Ash[buf][t * 2 + k2][(size_t)l * 8]);
          acc[t] = __builtin_amdgcn_mfma_f32_16x16x32_bf16(a, wf[s * 2 + k2],
                                                           acc[t], 0, 0, 0);
        }
    }
#undef STAGE

    // epilogue: 4 batches of 32 rows
    for (int b = 0; b < 4; ++b) {
      __syncthreads();
#pragma unroll
      for (int h = 0; h < 2; ++h) {
        int t = 2 * b + h;
#pragma unroll
        for (int i = 0; i < 4; ++i) {
          int r = h * 16 + ((l >> 4) << 2) + i;
          ssc[r][w * 16 + (l & 15)] = fmaf(acc[t][i], -0.5f, myc);
        }
      }
      __syncthreads();
      if (tid < 128) {                       // per-row-quarter top-4 of 32
        int r = tid >> 2, q = tid & 3;
        u64 top[4] = {0, 0, 0, 0};
        for (int jj = 0; jj < 32; ++jj) {
          int col = q * 32 + jj;
          u32 bits = __float_as_uint(ssc[r][col]);
          bits ^= (bits >> 31) ? 0xFFFFFFFFu : 0x80000000u;
          u64 key = ((u64)bits << 32) | (u32)col;
          if (key > top[3]) {
            top[3] = key;
            for (int z = 3; z > 0 && top[z] > top[z - 1]; --z) {
              u64 tt = top[z]; top[z] = top[z - 1]; top[z - 1] = tt;
            }
          }
        }
        for (int z = 0; z < 4; ++z) ssel[r][q][z] = top[z];
      }
      __syncthreads();
      if (tid < 32) {                        // merge 16 -> top-4, emit
        int r = tid;
        u64 top[4] = {0, 0, 0, 0};
        for (int q = 0; q < 4; ++q)
          for (int z = 0; z < 4; ++z) {
            u64 key = ssel[r][q][z];
            if (key > top[3]) {
              top[3] = key;
              for (int y = 3; y > 0 && top[y] > top[y - 1]; --y) {
                u64 tt = top[y]; top[y] = top[y - 1]; top[y - 1] = tt;
              }
            }
          }
        int rowg = mc * 128 + b * 32 + r;
        size_t base = ((size_t)rowg * NBLK + blockIdx.x) * 4;
        for (int z = 0; z < 4; ++z) {
          u32 bits = (u32)(top[z] >> 32);
          bits ^= (bits >> 31) ? 0x80000000u : 0xFFFFFFFFu;
          cval[base + z] = __uint_as_float(bits);
          cidx[base + z] = blockIdx.x * 128 + (int)(top[z] & 0xFFFFu);
        }
      }
    }
  }
}

// ---------------------------------------------------------------------------
// Kernel 4: per-row finalize. Merge 2048 cands -> approx top-64, exact fp32
// lp for those, exact top-32, softmax, weighted gather of outputs rows.
__global__ __launch_bounds__(256)
void finalize(const float* __restrict__ x, const float* __restrict__ mean,
              const float* __restrict__ stdd, const float* __restrict__ outs,
              const float* __restrict__ cval, const int* __restrict__ cidx,
              float* __restrict__ out) {
  __shared__ float cv[2048];
  __shared__ int ciL[2048];
  __shared__ float xr[256];
  __shared__ float part[256];
  __shared__ float lpv[64];
  __shared__ int selk[64];
  __shared__ float ew[32];
  __shared__ int kf[32];
  __shared__ float invs_sh;
  int tid = threadIdx.x;
  int row = blockIdx.x;

  for (int i = tid; i < 2048; i += 256) {
    cv[i] = cval[(size_t)row * 2048 + i];
    ciL[i] = cidx[(size_t)row * 2048 + i];
  }
  xr[tid] = x[(size_t)row * DDIM + tid];
  __syncthreads();

  if (tid < 64) {                       // wave 0: extract approx top-64 of 2048
    int l = tid;
    u64 lst[4] = {0, 0, 0, 0};
    u32 mask = 0;
    // build local (lane) top-4 over j = i*64 + l, i=0..31, skipping mask
    auto build = [&]() {
      lst[0] = lst[1] = lst[2] = lst[3] = 0;
      for (int i = 0; i < 32; ++i) {
        if (mask & (1u << i)) continue;
        int j = i * 64 + l;
        u32 bits = __float_as_uint(cv[j]);
        bits ^= (bits >> 31) ? 0xFFFFFFFFu : 0x80000000u;
        u64 key = ((u64)bits << 32) | (u32)j;
        if (key > lst[3]) {
          lst[3] = key;
          for (int z = 3; z > 0 && lst[z] > lst[z - 1]; --z) {
            u64 t = lst[z]; lst[z] = lst[z - 1]; lst[z - 1] = t;
          }
        }
      }
    };
    build();
    for (int it = 0; it < 64; ++it) {
      u64 m = lst[0];
      for (int d = 1; d < 64; d <<= 1) {
        u64 o = __shfl_xor(m, d);
        if (o > m) m = o;
      }
      int j = (int)(u32)(m & 0xFFFFFFFFu);
      if ((j & 63) == l) {
        mask |= 1u << (j >> 6);
        lst[0] = lst[1]; lst[1] = lst[2]; lst[2] = lst[3]; lst[3] = 0;
        if (lst[0] == 0) build();
      }
      if (l == 0) selk[it] = ciL[j];
    }
  }
  __syncthreads();

  {                                      // exact fp32 lp for 64 cands, 4 thr each
    int j = tid >> 2, q = tid & 3;
    int k = selk[j];
    const float* mr = mean + (size_t)k * DDIM + q * 64;
    const float* sr = stdd + (size_t)k * DDIM + q * 64;
    float s2 = 0.f, ls = 0.f;
    for (int i = 0; i < 16; ++i) {
      float4 m4 = *(const float4*)(mr + 4 * i);
      float4 s4 = *(const float4*)(sr + 4 * i);
      float4 x4 = *(const float4*)(&xr[q * 64 + 4 * i]);
      { float is = 1.f / s4.x; float df = (x4.x - m4.x) * is; s2 += df * df; ls += logf(s4.x); }
      { float is = 1.f / s4.y; float df = (x4.y - m4.y) * is; s2 += df * df; ls += logf(s4.y); }
      { float is = 1.f / s4.z; float df = (x4.z - m4.z) * is; s2 += df * df; ls += logf(s4.z); }
      { float is = 1.f / s4.w; float df = (x4.w - m4.w) * is; s2 += df * df; ls += logf(s4.w); }
    }
    part[tid] = -0.5f * s2 - ls;
  }
  __syncthreads();
  if (tid < 64)
    lpv[tid] = part[tid * 4] + part[tid * 4 + 1] + part[tid * 4 + 2] +
               part[tid * 4 + 3] - LOG2PI_TERM;
  __syncthreads();

  if (tid < 64) {                        // exact top-32 + softmax (wave 0)
    int l = tid;
    u32 bits = __float_as_uint(lpv[l]);
    bits ^= (bits >> 31) ? 0xFFFFFFFFu : 0x80000000u;
    u64 key = ((u64)bits << 32) | (u32)l;
    float maxlp = 0.f, ssum = 0.f;
    for (int it = 0; it < 32; ++it) {
      u64 m = key;
      for (int d = 1; d < 64; d <<= 1) {
        u64 o = __shfl_xor(m, d);
        if (o > m) m = o;
      }
      int j = (int)(u32)(m & 0xFFFFFFFFu);
      u32 vb = (u32)(m >> 32);
      vb ^= (vb >> 31) ? 0x80000000u : 0xFFFFFFFFu;
      float lp = __uint_as_float(vb);
      if (it == 0) maxlp = lp;
      float e = expf(lp - maxlp);
      ssum += e;
      if (l == 0) { ew[it] = e; kf[it] = selk[j]; }
      if (j == l) key = 0;
    }
    if (l == 0) invs_sh = 1.0f / ssum;
  }
  __syncthreads();

  {                                      // weighted gather: one output elem/thread
    float a = 0.f;
    for (int i = 0; i < 32; ++i)
      a += ew[i] * outs[(size_t)kf[i] * ODIM + tid];
    out[(size_t)row * ODIM + tid] = a * invs_sh;
  }
}

// ---------------------------------------------------------------------------
extern "C" void kernel_launch(void* const* d_in, const int* in_sizes, int n_in,
                              void* d_out, int out_size, void* d_ws, size_t ws_size,
                              hipStream_t stream) {
  const float* x = (const float*)d_in[0];
  const float* mean = (const float*)d_in[1];
  const float* stdd = (const float*)d_in[2];
  const float* outs = (const float*)d_in[3];
  char* ws = (char*)d_ws;
  u16* A_ws = (u16*)(ws + WS_A);
  u16* W_ws = (u16*)(ws + WS_W);
  float* ck = (float*)(ws + WS_CONST);
  float* cval = (float*)(ws + WS_CVAL);
  int* cidx = (int*)(ws + WS_CIDX);

  prep_A<<<64, 256, 0, stream>>>(x, A_ws);
  prep_W<<<1024, 256, 0, stream>>>(mean, stdd, W_ws, ck);
  main_gemm<<<NBLK, 512, 0, stream>>>(A_ws, W_ws, ck, cval, cidx);
  finalize<<<BROWS, 256, 0, stream>>>(x, mean, stdd, outs, cval, cidx,
                                      (float*)d_out);
}

// Round 2
// 541.181 us; speedup vs baseline: 1.8410x; 1.8410x over previous
//
#include <hip/hip_runtime.h>
#include <stdint.h>

// Problem constants
#define KCOMP 65536
#define DDIM  256
#define ODIM  256
#define BROWS 1024
#define NBLK  256            // main grid: KCOMP / 256 comps per block
#define LOG2PI_TERM 235.2482645f   // 0.5 * D * ln(2*pi)

typedef float f32x4 __attribute__((ext_vector_type(4)));
typedef __bf16 bf16x8 __attribute__((ext_vector_type(8)));
typedef unsigned int u32;
typedef unsigned long long u64;
typedef unsigned short u16;

typedef __attribute__((address_space(1))) const u32 gconst_u32;
typedef __attribute__((address_space(3))) u32 lds_u32;

__device__ __forceinline__ u16 f2bf(float f) {
  u32 b = __float_as_uint(f);
  b += 0x7FFFu + ((b >> 16) & 1u);
  return (u16)(b >> 16);
}
// monotone float->u32 key transform
__device__ __forceinline__ u32 fkey(float f) {
  u32 b = __float_as_uint(f);
  return b ^ ((b >> 31) ? 0xFFFFFFFFu : 0x80000000u);
}
__device__ __forceinline__ float keyf(u32 b) {
  b ^= (b >> 31) ? 0x80000000u : 0xFFFFFFFFu;
  return __uint_as_float(b);
}

// ws layout (bytes). Total ~73.3 MB.
#define WS_A     0                          // 1 MB   A frag-linear [64 tile][16 cc][64 lane][16B]
#define WS_W     (1u << 20)                 // 64 MB  W frag-linear [4096 grp][16 cc][64 lane][16B]
#define WS_CONST (WS_W + (64u << 20))       // 256 KB per-comp const
#define WS_CVAL  (WS_CONST + (256u << 10))  // 4 MB   cand values [1024][256][4]
#define WS_CIDX  (WS_CVAL + (4u << 20))     // 4 MB   cand indices

// ---------------------------------------------------------------------------
// Kernel 1: A features. kappa=2d -> x_d^2 ; kappa=2d+1 -> -2 x_d (MFMA A layout).
__global__ void prep_A(const float* __restrict__ x, u16* __restrict__ A) {
  int l = threadIdx.x & 63;
  int wv = threadIdx.x >> 6;
  int t = blockIdx.x;                 // m16 tile 0..63
  int row = t * 16 + (l & 15);
  for (int u = 0; u < 4; ++u) {
    int cc = wv * 4 + u;              // 0..15
    int d0 = cc * 16 + ((l >> 4) << 2);
    float4 xv = *(const float4*)(x + (size_t)row * DDIM + d0);
    float xs[4] = {xv.x, xv.y, xv.z, xv.w};
    uint4 v;
    u32 wds[4];
    for (int e = 0; e < 4; ++e)
      wds[e] = (u32)f2bf(xs[e] * xs[e]) | ((u32)f2bf(-2.0f * xs[e]) << 16);
    v.x = wds[0]; v.y = wds[1]; v.z = wds[2]; v.w = wds[3];
    *(uint4*)(A + ((size_t)(t * 16 + cc) * 64 + l) * 8) = v;
  }
}

// ---------------------------------------------------------------------------
// Kernel 2: W weights (kappa=2d -> inv_var ; 2d+1 -> mean*inv_var, MFMA B
// layout) + per-comp const = -0.5*sum(m^2 iv) - sum(log s) - 0.5 D ln(2pi).
__global__ void prep_W(const float* __restrict__ mean, const float* __restrict__ stdd,
                       u16* __restrict__ W, float* __restrict__ ck) {
  int l = threadIdx.x & 63;
  int wv = threadIdx.x >> 6;
  int g = blockIdx.x * 4 + wv;        // 16-comp group 0..4095
  for (int p = 0; p < 16; ++p) {
    int comp = g * 16 + p;
    float4 m4 = *(const float4*)(mean + (size_t)comp * DDIM + l * 4);
    float4 s4 = *(const float4*)(stdd + (size_t)comp * DDIM + l * 4);
    float ms[4] = {m4.x, m4.y, m4.z, m4.w};
    float ss[4] = {s4.x, s4.y, s4.z, s4.w};
    u32 wds[4];
    float gsum = 0.f;
    for (int e = 0; e < 4; ++e) {
      float iv = 1.0f / (ss[e] * ss[e]);
      float miv = ms[e] * iv;
      wds[e] = (u32)f2bf(iv) | ((u32)f2bf(miv) << 16);
      gsum += -0.5f * ms[e] * miv - logf(ss[e]);
    }
    for (int d = 1; d < 64; d <<= 1) gsum += __shfl_xor(gsum, d);
    if (l == 0) ck[comp] = gsum - LOG2PI_TERM;
    uint4 v; v.x = wds[0]; v.y = wds[1]; v.z = wds[2]; v.w = wds[3];
    size_t slot = (size_t)(g * 16 + (l >> 2)) * 64 + (size_t)((l & 3) * 16 + p);
    *(uint4*)(W + slot * 8) = v;
  }
}

// ---------------------------------------------------------------------------
// Kernel 3: main GEMM + fused selection. 256 blocks x 512 thr (8 waves).
// Block owns 256 comps; wave holds 32 comps of W in regs (2 B-frag sets,
// 128 VGPR) so each A-frag LDS read feeds 2 MFMAs. A streams via
// global_load_lds into a 128 KB double-buffered LDS (4 m16-tiles = 64 rows
// per stage, 16 stages, ONE barrier per stage). Selection: per-row top-2
// over wave's 32 comps via shfl butterfly, per-stage merge 16->4 by wave 0.
__global__ __launch_bounds__(512, 2)
void main_gemm(const u16* __restrict__ A_ws, const u16* __restrict__ W_ws,
               const float* __restrict__ ck, float* __restrict__ cval,
               int* __restrict__ cidx) {
  __shared__ u16 Ash[2][64][512];      // 128 KB: [buf][cell = t*16+cc][lane*8]
  __shared__ u32 whi[2][64][17];       // 8.5 KB, odd dword stride (bank-safe)
  __shared__ u32 wlo[2][64][17];       // 8.5 KB
  int tid = threadIdx.x, l = tid & 63, w = tid >> 6;
  int g0 = blockIdx.x * 16 + w * 2;    // two 16-comp groups per wave

  bf16x8 wfA[16], wfB[16];
#pragma unroll
  for (int cc = 0; cc < 16; ++cc) {
    wfA[cc] = *(const bf16x8*)(W_ws + ((size_t)(g0 * 16 + cc) * 64 + l) * 8);
    wfB[cc] = *(const bf16x8*)(W_ws + ((size_t)((g0 + 1) * 16 + cc) * 64 + l) * 8);
  }
  float mycA = ck[g0 * 16 + (l & 15)];
  float mycB = ck[(g0 + 1) * 16 + (l & 15)];
  u32 compA = (u32)(g0 * 16 + (l & 15));
  u32 compB = (u32)((g0 + 1) * 16 + (l & 15));

  // stage s (4 tiles, 64 cells of 1 KB) into buf b; wave w stages 8 cells
#define ISSUE(S, B)                                                            \
  {                                                                            \
    _Pragma("unroll")                                                          \
    for (int u = 0; u < 8; ++u) {                                              \
      int cell = w * 8 + u;                                                    \
      const u16* gsrc = A_ws +                                                 \
        ((size_t)((S) * 4 + (cell >> 4)) * 16 + (cell & 15)) * 512 +           \
        (size_t)l * 8;                                                         \
      __builtin_amdgcn_global_load_lds((gconst_u32*)gsrc,                      \
          (lds_u32*)&Ash[B][cell][0], 16, 0, 0);                               \
    }                                                                          \
  }

  // merge 16 candidate keys -> top-4 for the 64 rows of stage ST from buf B
#define MERGE_EMIT(ST, B)                                                      \
  {                                                                            \
    int r = tid;                                                               \
    u64 top[4] = {0, 0, 0, 0};                                                 \
    _Pragma("unroll")                                                          \
    for (int j = 0; j < 16; ++j) {                                             \
      u64 key = ((u64)whi[B][r][j] << 32) | (u64)wlo[B][r][j];                 \
      if (key > top[3]) {                                                      \
        top[3] = key;                                                          \
        for (int z = 3; z > 0 && top[z] > top[z - 1]; --z) {                   \
          u64 tt = top[z]; top[z] = top[z - 1]; top[z - 1] = tt;               \
        }                                                                      \
      }                                                                        \
    }                                                                          \
    int rowg = (ST) * 64 + r;                                                  \
    size_t base = ((size_t)rowg * NBLK + blockIdx.x) * 4;                      \
    for (int z = 0; z < 4; ++z) {                                              \
      cval[base + z] = keyf((u32)(top[z] >> 32));                              \
      cidx[base + z] = (int)(u32)top[z];                                       \
    }                                                                          \
  }

  ISSUE(0, 0)
  for (int s = 0; s < 16; ++s) {
    int p = s & 1;
    __syncthreads();                   // staging of buf p done; whi[p^1] ready
    if (s < 15) ISSUE(s + 1, p ^ 1)
    if (s > 0 && tid < 64) MERGE_EMIT(s - 1, p ^ 1)

    f32x4 aA[4], aB[4];
#pragma unroll
    for (int t = 0; t < 4; ++t) {
      aA[t] = (f32x4){0.f, 0.f, 0.f, 0.f};
      aB[t] = (f32x4){0.f, 0.f, 0.f, 0.f};
    }
#pragma unroll
    for (int cc = 0; cc < 16; ++cc)
#pragma unroll
      for (int t = 0; t < 4; ++t) {
        bf16x8 a = *(const bf16x8*)(&Ash[p][t * 16 + cc][(size_t)l * 8]);
        aA[t] = __builtin_amdgcn_mfma_f32_16x16x32_bf16(a, wfA[cc], aA[t], 0, 0, 0);
        aB[t] = __builtin_amdgcn_mfma_f32_16x16x32_bf16(a, wfB[cc], aB[t], 0, 0, 0);
      }

    // selection: per-row top-2 over this wave's 32 comps (reg butterfly)
#pragma unroll
    for (int t = 0; t < 4; ++t)
#pragma unroll
      for (int i = 0; i < 4; ++i) {
        float sA = fmaf(aA[t][i], -0.5f, mycA);
        float sB = fmaf(aB[t][i], -0.5f, mycB);
        u64 kA = ((u64)fkey(sA) << 32) | compA;
        u64 kB = ((u64)fkey(sB) << 32) | compB;
        u64 m1 = kA > kB ? kA : kB;
        u64 m2 = kA > kB ? kB : kA;
#pragma unroll
        for (int msk = 1; msk < 16; msk <<= 1) {
          u64 o1 = __shfl_xor(m1, msk);
          u64 o2 = __shfl_xor(m2, msk);
          u64 hi = m1 > o1 ? m1 : o1;
          u64 sc = m1 > o1 ? m2 : o2;        // runner-up on winner's side
          u64 lo = m1 > o1 ? o1 : m1;        // loser of the firsts
          m2 = sc > lo ? sc : lo;
          m1 = hi;
        }
        int rl = t * 16 + ((l >> 4) << 2) + i;
        if ((l & 15) == 0) { whi[p][rl][w * 2] = (u32)(m1 >> 32); wlo[p][rl][w * 2] = (u32)m1; }
        if ((l & 15) == 1) { whi[p][rl][w * 2 + 1] = (u32)(m2 >> 32); wlo[p][rl][w * 2 + 1] = (u32)m2; }
      }
  }
  __syncthreads();
  if (tid < 64) MERGE_EMIT(15, 1)
#undef ISSUE
#undef MERGE_EMIT
}

// ---------------------------------------------------------------------------
// Kernel 4: per-row finalize. 1024 cands -> 4 parallel per-wave exact top-16
// (union covers all non-negligible weights), exact fp32 lp for 64, exact
// top-32, softmax, weighted gather.
__global__ __launch_bounds__(256)
void finalize(const float* __restrict__ x, const float* __restrict__ mean,
              const float* __restrict__ stdd, const float* __restrict__ outs,
              const float* __restrict__ cval, const int* __restrict__ cidx,
              float* __restrict__ out) {
  __shared__ float cv[1024];
  __shared__ int ci[1024];
  __shared__ float xr[256];
  __shared__ float part[256];
  __shared__ float lpv[64];
  __shared__ int selk[64];
  __shared__ float ew[32];
  __shared__ int kf[32];
  __shared__ float invs_sh;
  int tid = threadIdx.x, l = tid & 63, v = tid >> 6;
  int row = blockIdx.x;

  for (int i = tid; i < 1024; i += 256) {
    cv[i] = cval[(size_t)row * 1024 + i];
    ci[i] = cidx[(size_t)row * 1024 + i];
  }
  xr[tid] = x[(size_t)row * DDIM + tid];
  __syncthreads();

  {  // wave v: exact top-16 of its 256 cands (4 per lane, sorted, extract 16)
    u64 loc[4];
#pragma unroll
    for (int i = 0; i < 4; ++i) {
      int j = v * 256 + i * 64 + l;
      loc[i] = ((u64)fkey(cv[j]) << 32) | (u32)j;
    }
    // descending sort-4 network
#define CSW(a, b) { if (loc[a] < loc[b]) { u64 t = loc[a]; loc[a] = loc[b]; loc[b] = t; } }
    CSW(0, 1) CSW(2, 3) CSW(0, 2) CSW(1, 3) CSW(1, 2)
#undef CSW
    for (int it = 0; it < 16; ++it) {
      u64 m = loc[0];
      for (int d = 1; d < 64; d <<= 1) {
        u64 o = __shfl_xor(m, d);
        if (o > m) m = o;
      }
      if (m == loc[0]) { loc[0] = loc[1]; loc[1] = loc[2]; loc[2] = loc[3]; loc[3] = 0; }
      if (l == 0) selk[v * 16 + it] = ci[(u32)m];
    }
  }
  __syncthreads();

  {  // exact fp32 lp for 64 cands, 4 threads each
    int j = tid >> 2, q = tid & 3;
    int k = selk[j];
    const float* mr = mean + (size_t)k * DDIM + q * 64;
    const float* sr = stdd + (size_t)k * DDIM + q * 64;
    float s2 = 0.f, ls = 0.f;
    for (int i = 0; i < 16; ++i) {
      float4 m4 = *(const float4*)(mr + 4 * i);
      float4 s4 = *(const float4*)(sr + 4 * i);
      float4 x4 = *(const float4*)(&xr[q * 64 + 4 * i]);
      { float is = 1.f / s4.x; float df = (x4.x - m4.x) * is; s2 += df * df; ls += logf(s4.x); }
      { float is = 1.f / s4.y; float df = (x4.y - m4.y) * is; s2 += df * df; ls += logf(s4.y); }
      { float is = 1.f / s4.z; float df = (x4.z - m4.z) * is; s2 += df * df; ls += logf(s4.z); }
      { float is = 1.f / s4.w; float df = (x4.w - m4.w) * is; s2 += df * df; ls += logf(s4.w); }
    }
    part[tid] = -0.5f * s2 - ls;
  }
  __syncthreads();
  if (tid < 64)
    lpv[tid] = part[tid * 4] + part[tid * 4 + 1] + part[tid * 4 + 2] +
               part[tid * 4 + 3] - LOG2PI_TERM;
  __syncthreads();

  if (tid < 64) {                        // exact top-32 + softmax (wave 0)
    u32 bits = fkey(lpv[l]);
    u64 key = ((u64)bits << 32) | (u32)l;
    float maxlp = 0.f, ssum = 0.f;
    for (int it = 0; it < 32; ++it) {
      u64 m = key;
      for (int d = 1; d < 64; d <<= 1) {
        u64 o = __shfl_xor(m, d);
        if (o > m) m = o;
      }
      int j = (int)(u32)m;
      float lp = keyf((u32)(m >> 32));
      if (it == 0) maxlp = lp;
      float e = expf(lp - maxlp);
      ssum += e;
      if (l == 0) { ew[it] = e; kf[it] = selk[j]; }
      if (j == l) key = 0;
    }
    if (l == 0) invs_sh = 1.0f / ssum;
  }
  __syncthreads();

  {  // weighted gather: one output element per thread
    float a = 0.f;
    for (int i = 0; i < 32; ++i)
      a += ew[i] * outs[(size_t)kf[i] * ODIM + tid];
    out[(size_t)row * ODIM + tid] = a * invs_sh;
  }
}

// ---------------------------------------------------------------------------
extern "C" void kernel_launch(void* const* d_in, const int* in_sizes, int n_in,
                              void* d_out, int out_size, void* d_ws, size_t ws_size,
                              hipStream_t stream) {
  const float* x = (const float*)d_in[0];
  const float* mean = (const float*)d_in[1];
  const float* stdd = (const float*)d_in[2];
  const float* outs = (const float*)d_in[3];
  char* ws = (char*)d_ws;
  u16* A_ws = (u16*)(ws + WS_A);
  u16* W_ws = (u16*)(ws + WS_W);
  float* ck = (float*)(ws + WS_CONST);
  float* cval = (float*)(ws + WS_CVAL);
  int* cidx = (int*)(ws + WS_CIDX);

  prep_A<<<64, 256, 0, stream>>>(x, A_ws);
  prep_W<<<1024, 256, 0, stream>>>(mean, stdd, W_ws, ck);
  main_gemm<<<NBLK, 512, 0, stream>>>(A_ws, W_ws, ck, cval, cidx);
  finalize<<<BROWS, 256, 0, stream>>>(x, mean, stdd, outs, cval, cidx,
                                      (float*)d_out);
}

// Round 3
// 455.684 us; speedup vs baseline: 2.1865x; 1.1876x over previous
//
#include <hip/hip_runtime.h>
#include <stdint.h>

// Problem constants
#define KCOMP 65536
#define DDIM  256
#define ODIM  256
#define BROWS 1024
#define NBLK  512            // main grid: KCOMP / 128 comps per block
#define LOG2PI_TERM 235.2482645f   // 0.5 * D * ln(2*pi)

typedef float f32x4 __attribute__((ext_vector_type(4)));
typedef __bf16 bf16x8 __attribute__((ext_vector_type(8)));
typedef unsigned int u32;
typedef unsigned long long u64;
typedef unsigned short u16;

typedef __attribute__((address_space(1))) const u32 gconst_u32;
typedef __attribute__((address_space(3))) u32 lds_u32;

__device__ __forceinline__ u16 f2bf(float f) {
  u32 b = __float_as_uint(f);
  b += 0x7FFFu + ((b >> 16) & 1u);
  return (u16)(b >> 16);
}
// monotone float->u32 key transform
__device__ __forceinline__ u32 fkey(float f) {
  u32 b = __float_as_uint(f);
  return b ^ ((b >> 31) ? 0xFFFFFFFFu : 0x80000000u);
}

// ws layout (bytes). Total ~73.3 MB.
#define WS_A     0                          // 1 MB   A frag-linear [64 tile][16 cc][64 lane][16B]
#define WS_W     (1u << 20)                 // 64 MB  W frag-linear [4096 grp][16 cc][64 lane][16B]
#define WS_CONST (WS_W + (64u << 20))       // 256 KB per-comp const
#define WS_KEY   (WS_CONST + (256u << 10))  // 8 MB   cand keys [1024][512 blk][4]

// ---------------------------------------------------------------------------
// Kernel 1: A features. kappa=2d -> x_d^2 ; kappa=2d+1 -> -2 x_d (MFMA A layout).
__global__ void prep_A(const float* __restrict__ x, u16* __restrict__ A) {
  int l = threadIdx.x & 63;
  int wv = threadIdx.x >> 6;
  int t = blockIdx.x;                 // m16 tile 0..63
  int row = t * 16 + (l & 15);
  for (int u = 0; u < 4; ++u) {
    int cc = wv * 4 + u;              // 0..15
    int d0 = cc * 16 + ((l >> 4) << 2);
    float4 xv = *(const float4*)(x + (size_t)row * DDIM + d0);
    float xs[4] = {xv.x, xv.y, xv.z, xv.w};
    uint4 v;
    u32 wds[4];
    for (int e = 0; e < 4; ++e)
      wds[e] = (u32)f2bf(xs[e] * xs[e]) | ((u32)f2bf(-2.0f * xs[e]) << 16);
    v.x = wds[0]; v.y = wds[1]; v.z = wds[2]; v.w = wds[3];
    *(uint4*)(A + ((size_t)(t * 16 + cc) * 64 + l) * 8) = v;
  }
}

// ---------------------------------------------------------------------------
// Kernel 2: W weights (kappa=2d -> inv_var ; 2d+1 -> mean*inv_var, MFMA B
// layout) + per-comp const. Computes into an LDS transpose buffer so the
// global W writes are 64-lane x 16B fully-coalesced 1 KB lines (round-2's
// scattered 256B-stride stores were the suspected hidden ~100+ us).
__global__ __launch_bounds__(256)
void prep_W(const float* __restrict__ mean, const float* __restrict__ stdd,
            u16* __restrict__ W, float* __restrict__ ck) {
  __shared__ u32 ldsW[4][16][268];    // [wave][comp p][dim d], stride 268 (16B-aligned, bank-spread)
  int l = threadIdx.x & 63;
  int wv = threadIdx.x >> 6;
  int g = blockIdx.x * 4 + wv;        // 16-comp group 0..4095
  for (int p = 0; p < 16; ++p) {
    int comp = g * 16 + p;
    float4 m4 = *(const float4*)(mean + (size_t)comp * DDIM + l * 4);
    float4 s4 = *(const float4*)(stdd + (size_t)comp * DDIM + l * 4);
    float ms[4] = {m4.x, m4.y, m4.z, m4.w};
    float ss[4] = {s4.x, s4.y, s4.z, s4.w};
    u32 wds[4];
    float gsum = 0.f;
    for (int e = 0; e < 4; ++e) {
      float iv = 1.0f / (ss[e] * ss[e]);
      float miv = ms[e] * iv;
      wds[e] = (u32)f2bf(iv) | ((u32)f2bf(miv) << 16);
      gsum += -0.5f * ms[e] * miv - logf(ss[e]);
    }
    for (int d = 1; d < 64; d <<= 1) gsum += __shfl_xor(gsum, d);
    if (l == 0) ck[comp] = gsum - LOG2PI_TERM;
    uint4 v; v.x = wds[0]; v.y = wds[1]; v.z = wds[2]; v.w = wds[3];
    *(uint4*)&ldsW[wv][p][l * 4] = v;     // lane l holds dims 4l..4l+3
  }
  __syncthreads();
  // frag lane l of (g,cc) needs comp l&15, dims cc*16 + (l>>4)*4 + 0..3
  for (int cc = 0; cc < 16; ++cc) {
    uint4 v = *(const uint4*)&ldsW[wv][l & 15][cc * 16 + ((l >> 4) << 2)];
    *(uint4*)(W + ((size_t)(g * 16 + cc) * 64 + l) * 8) = v;
  }
}

// ---------------------------------------------------------------------------
// Kernel 3: main GEMM + fused selection. 512 blocks x 256 thr (4 waves).
// Block owns 128 comps; wave holds 32 comps of W in regs (2 B-frag sets).
// A streams via global_load_lds, 32-row double-buffered stages (64 KB LDS)
// -> 2 blocks/CU so barriers of one block overlap compute of the other.
// Selection: u32 packed keys (score-hi24 | comp7), per-row top-2 butterfly,
// per-stage merge 8 -> top-4, single uint4 store per row.
__global__ __launch_bounds__(256, 2)
void main_gemm(const u16* __restrict__ A_ws, const u16* __restrict__ W_ws,
               const float* __restrict__ ck, u32* __restrict__ ckey) {
  __shared__ u16 Ash[2][32][512];      // 64 KB: [buf][cell = t*16+cc][lane*8]
  __shared__ u32 wsel[2][32][9];       // 2.3 KB: [buf][row][4 waves x 2 + pad]
  int tid = threadIdx.x, l = tid & 63, w = tid >> 6;
  int nb = blockIdx.x;
  int g0 = nb * 8 + w * 2;             // two 16-comp groups per wave

  bf16x8 wfA[16], wfB[16];
#pragma unroll
  for (int cc = 0; cc < 16; ++cc) {
    wfA[cc] = *(const bf16x8*)(W_ws + ((size_t)(g0 * 16 + cc) * 64 + l) * 8);
    wfB[cc] = *(const bf16x8*)(W_ws + ((size_t)((g0 + 1) * 16 + cc) * 64 + l) * 8);
  }
  float mycA = ck[g0 * 16 + (l & 15)];
  float mycB = ck[(g0 + 1) * 16 + (l & 15)];
  u32 cA = (u32)(w * 32 + (l & 15));   // local comp id 0..127
  u32 cB = cA + 16;

  // stage S (2 m16-tiles = 32 cells of 1 KB) into buf B; wave stages 8 cells
#define ISSUE(S, B)                                                            \
  {                                                                            \
    _Pragma("unroll")                                                          \
    for (int u = 0; u < 8; ++u) {                                              \
      int cell = w * 8 + u;                                                    \
      const u16* gsrc = A_ws +                                                 \
        ((size_t)((S) * 2 + (cell >> 4)) * 16 + (cell & 15)) * 512 +           \
        (size_t)l * 8;                                                         \
      __builtin_amdgcn_global_load_lds((gconst_u32*)gsrc,                      \
          (lds_u32*)&Ash[B][cell][0], 16, 0, 0);                               \
    }                                                                          \
  }

  // merge 8 keys -> top-4 for the 32 rows of stage ST from buf B, emit
#define MERGE_EMIT(ST, B)                                                      \
  {                                                                            \
    int r = tid;                                                               \
    u32 top[4] = {0, 0, 0, 0};                                                 \
    _Pragma("unroll")                                                          \
    for (int j = 0; j < 8; ++j) {                                              \
      u32 key = wsel[B][r][j];                                                 \
      if (key > top[3]) {                                                      \
        top[3] = key;                                                          \
        for (int z = 3; z > 0 && top[z] > top[z - 1]; --z) {                   \
          u32 tt = top[z]; top[z] = top[z - 1]; top[z - 1] = tt;               \
        }                                                                      \
      }                                                                        \
    }                                                                          \
    int rowg = (ST) * 32 + r;                                                  \
    uint4 ov; ov.x = top[0]; ov.y = top[1]; ov.z = top[2]; ov.w = top[3];      \
    *(uint4*)&ckey[((size_t)rowg * NBLK + nb) * 4] = ov;                       \
  }

  ISSUE(0, 0)
  for (int s = 0; s < 32; ++s) {
    int p = s & 1;
    __syncthreads();                   // staging of buf p done; wsel[p^1] ready
    if (s < 31) ISSUE(s + 1, p ^ 1)
    if (s > 0 && tid < 32) MERGE_EMIT(s - 1, p ^ 1)

    f32x4 aA[2], aB[2];
#pragma unroll
    for (int t = 0; t < 2; ++t) {
      aA[t] = (f32x4){0.f, 0.f, 0.f, 0.f};
      aB[t] = (f32x4){0.f, 0.f, 0.f, 0.f};
    }
#pragma unroll
    for (int cc = 0; cc < 16; ++cc)
#pragma unroll
      for (int t = 0; t < 2; ++t) {
        bf16x8 a = *(const bf16x8*)(&Ash[p][t * 16 + cc][(size_t)l * 8]);
        aA[t] = __builtin_amdgcn_mfma_f32_16x16x32_bf16(a, wfA[cc], aA[t], 0, 0, 0);
        aB[t] = __builtin_amdgcn_mfma_f32_16x16x32_bf16(a, wfB[cc], aB[t], 0, 0, 0);
      }

    // selection: per-row top-2 over wave's 32 comps, u32 packed keys
#pragma unroll
    for (int t = 0; t < 2; ++t)
#pragma unroll
      for (int i = 0; i < 4; ++i) {
        float sA = fmaf(aA[t][i], -0.5f, mycA);
        float sB = fmaf(aB[t][i], -0.5f, mycB);
        u32 kA = (fkey(sA) & 0xFFFFFF00u) | cA;
        u32 kB = (fkey(sB) & 0xFFFFFF00u) | cB;
        u32 m1 = kA > kB ? kA : kB;
        u32 m2 = kA > kB ? kB : kA;
#pragma unroll
        for (int msk = 1; msk < 16; msk <<= 1) {
          u32 o1 = (u32)__shfl_xor((int)m1, msk);
          u32 o2 = (u32)__shfl_xor((int)m2, msk);
          bool gt = m1 > o1;
          u32 r2 = gt ? m2 : o2;       // runner-up on winner's side
          u32 lo = gt ? o1 : m1;       // loser of the firsts
          m1 = gt ? m1 : o1;
          m2 = r2 > lo ? r2 : lo;
        }
        int rl = t * 16 + ((l >> 4) << 2) + i;
        if ((l & 15) == 0) wsel[p][rl][w * 2] = m1;
        else if ((l & 15) == 1) wsel[p][rl][w * 2 + 1] = m2;
      }
  }
  __syncthreads();
  if (tid < 32) MERGE_EMIT(31, 1)
#undef ISSUE
#undef MERGE_EMIT
}

// ---------------------------------------------------------------------------
// Kernel 4: per-row finalize. 2048 u32 cand keys -> 4 parallel per-wave exact
// top-16 (sorted local-8 + 64-lane extraction), decode comps, exact fp32 lp
// for 64, exact top-32, softmax, weighted gather.
__global__ __launch_bounds__(256)
void finalize(const float* __restrict__ x, const float* __restrict__ mean,
              const float* __restrict__ stdd, const float* __restrict__ outs,
              const u32* __restrict__ ckey, float* __restrict__ out) {
  __shared__ u32 cksh[2048];
  __shared__ float xr[256];
  __shared__ float part[256];
  __shared__ float lpv[64];
  __shared__ int selk[64];
  __shared__ float ew[32];
  __shared__ int kf[32];
  __shared__ float invs_sh;
  int tid = threadIdx.x, l = tid & 63, v = tid >> 6;
  int row = blockIdx.x;

  for (int i = tid; i < 2048; i += 256)
    cksh[i] = ckey[(size_t)row * 2048 + i];
  xr[tid] = x[(size_t)row * DDIM + tid];
  __syncthreads();

  {  // wave v: exact top-16 of its 512 cands (8/lane sorted, extract 16)
    u64 loc[8];
#pragma unroll
    for (int i = 0; i < 8; ++i) {
      int j = v * 512 + i * 64 + l;
      loc[i] = ((u64)cksh[j] << 32) | (u32)j;
    }
    // descending odd-even mergesort-8 (19 comparators)
#define CSW(a, b) { if (loc[a] < loc[b]) { u64 t = loc[a]; loc[a] = loc[b]; loc[b] = t; } }
    CSW(0,1) CSW(2,3) CSW(4,5) CSW(6,7)
    CSW(0,2) CSW(1,3) CSW(4,6) CSW(5,7)
    CSW(1,2) CSW(5,6)
    CSW(0,4) CSW(1,5) CSW(2,6) CSW(3,7)
    CSW(2,4) CSW(3,5)
    CSW(1,2) CSW(3,4) CSW(5,6)
#undef CSW
    for (int it = 0; it < 16; ++it) {
      u64 m = loc[0];
      for (int d = 1; d < 64; d <<= 1) {
        u64 o = __shfl_xor(m, d);
        if (o > m) m = o;
      }
      if (m == loc[0]) {
#pragma unroll
        for (int z = 0; z < 7; ++z) loc[z] = loc[z + 1];
        loc[7] = 0;
      }
      if (l == 0) {
        u32 j = (u32)m;                 // local cand index -> block = j>>2
        u32 key = (u32)(m >> 32);
        selk[v * 16 + it] = (int)((j >> 2) * 128 + (key & 0xFFu));
      }
    }
  }
  __syncthreads();

  {  // exact fp32 lp for 64 cands, 4 threads each
    int j = tid >> 2, q = tid & 3;
    int k = selk[j];
    const float* mr = mean + (size_t)k * DDIM + q * 64;
    const float* sr = stdd + (size_t)k * DDIM + q * 64;
    float s2 = 0.f, ls = 0.f;
    for (int i = 0; i < 16; ++i) {
      float4 m4 = *(const float4*)(mr + 4 * i);
      float4 s4 = *(const float4*)(sr + 4 * i);
      float4 x4 = *(const float4*)(&xr[q * 64 + 4 * i]);
      { float is = 1.f / s4.x; float df = (x4.x - m4.x) * is; s2 += df * df; ls += logf(s4.x); }
      { float is = 1.f / s4.y; float df = (x4.y - m4.y) * is; s2 += df * df; ls += logf(s4.y); }
      { float is = 1.f / s4.z; float df = (x4.z - m4.z) * is; s2 += df * df; ls += logf(s4.z); }
      { float is = 1.f / s4.w; float df = (x4.w - m4.w) * is; s2 += df * df; ls += logf(s4.w); }
    }
    part[tid] = -0.5f * s2 - ls;
  }
  __syncthreads();
  if (tid < 64)
    lpv[tid] = part[tid * 4] + part[tid * 4 + 1] + part[tid * 4 + 2] +
               part[tid * 4 + 3] - LOG2PI_TERM;
  __syncthreads();

  if (tid < 64) {                        // exact top-32 + softmax (wave 0)
    u64 key = ((u64)fkey(lpv[l]) << 32) | (u32)l;
    float maxlp = 0.f, ssum = 0.f;
    for (int it = 0; it < 32; ++it) {
      u64 m = key;
      for (int d = 1; d < 64; d <<= 1) {
        u64 o = __shfl_xor(m, d);
        if (o > m) m = o;
      }
      int j = (int)(u32)m;
      u32 vb = (u32)(m >> 32);
      vb ^= (vb >> 31) ? 0x80000000u : 0xFFFFFFFFu;
      float lp = __uint_as_float(vb);
      if (it == 0) maxlp = lp;
      float e = expf(lp - maxlp);
      ssum += e;
      if (l == 0) { ew[it] = e; kf[it] = selk[j]; }
      if (j == l) key = 0;
    }
    if (l == 0) invs_sh = 1.0f / ssum;
  }
  __syncthreads();

  {  // weighted gather: one output element per thread
    float a = 0.f;
    for (int i = 0; i < 32; ++i)
      a += ew[i] * outs[(size_t)kf[i] * ODIM + tid];
    out[(size_t)row * ODIM + tid] = a * invs_sh;
  }
}

// ---------------------------------------------------------------------------
extern "C" void kernel_launch(void* const* d_in, const int* in_sizes, int n_in,
                              void* d_out, int out_size, void* d_ws, size_t ws_size,
                              hipStream_t stream) {
  const float* x = (const float*)d_in[0];
  const float* mean = (const float*)d_in[1];
  const float* stdd = (const float*)d_in[2];
  const float* outs = (const float*)d_in[3];
  char* ws = (char*)d_ws;
  u16* A_ws = (u16*)(ws + WS_A);
  u16* W_ws = (u16*)(ws + WS_W);
  float* ck = (float*)(ws + WS_CONST);
  u32* ckey = (u32*)(ws + WS_KEY);

  prep_A<<<64, 256, 0, stream>>>(x, A_ws);
  prep_W<<<1024, 256, 0, stream>>>(mean, stdd, W_ws, ck);
  main_gemm<<<NBLK, 256, 0, stream>>>(A_ws, W_ws, ck, ckey);
  finalize<<<BROWS, 256, 0, stream>>>(x, mean, stdd, outs, ckey,
                                      (float*)d_out);
}

// Round 4
// 419.642 us; speedup vs baseline: 2.3742x; 1.0859x over previous
//
#include <hip/hip_runtime.h>
#include <stdint.h>

// Problem constants
#define KCOMP 65536
#define DDIM  256
#define ODIM  256
#define BROWS 1024
#define NCB   512            // comp-blocks: KCOMP / 128 comps per block
#define NBLK  1024           // main grid: NCB * 2 row-halves
#define LOG2PI_TERM 235.2482645f   // 0.5 * D * ln(2*pi)

typedef float f32x4 __attribute__((ext_vector_type(4)));
typedef __bf16 bf16x8 __attribute__((ext_vector_type(8)));
typedef unsigned int u32;
typedef unsigned long long u64;
typedef unsigned short u16;

typedef __attribute__((address_space(1))) const u32 gconst_u32;
typedef __attribute__((address_space(3))) u32 lds_u32;

__device__ __forceinline__ u16 f2bf(float f) {
  u32 b = __float_as_uint(f);
  b += 0x7FFFu + ((b >> 16) & 1u);
  return (u16)(b >> 16);
}
// monotone float->u32 key (used only in finalize, where sign varies)
__device__ __forceinline__ u32 fkey(float f) {
  u32 b = __float_as_uint(f);
  return b ^ ((b >> 31) ? 0xFFFFFFFFu : 0x80000000u);
}

// DPP row_ror:n control codes (rotate within 16-lane rows) — pure-VALU lane
// exchange; keeps the selection merge OFF the LDS pipe (round-3's bpermutes
// doubled LDS-pipe load: 82 of 164 us).
#define DPP_ROR1 0x121
#define DPP_ROR2 0x122
#define DPP_ROR4 0x124
#define DPP_ROR8 0x128

// ws layout (bytes). Total ~73.3 MB.
#define WS_A     0                          // 1 MB   A frag-linear [64 tile][16 cc][64 lane][16B]
#define WS_W     (1u << 20)                 // 64 MB  W frag-linear [4096 grp][16 cc][64 lane][16B]
#define WS_CONST (WS_W + (64u << 20))       // 256 KB per-comp const
#define WS_KEY   (WS_CONST + (256u << 10))  // 8 MB   cand keys [1024 row][512 cb][4]

// ---------------------------------------------------------------------------
// Kernel 1: A features. kappa=2d -> x_d^2 ; kappa=2d+1 -> -2 x_d (MFMA A layout).
__global__ void prep_A(const float* __restrict__ x, u16* __restrict__ A) {
  int l = threadIdx.x & 63;
  int wv = threadIdx.x >> 6;
  int t = blockIdx.x;                 // m16 tile 0..63
  int row = t * 16 + (l & 15);
  for (int u = 0; u < 4; ++u) {
    int cc = wv * 4 + u;              // 0..15
    int d0 = cc * 16 + ((l >> 4) << 2);
    float4 xv = *(const float4*)(x + (size_t)row * DDIM + d0);
    float xs[4] = {xv.x, xv.y, xv.z, xv.w};
    uint4 v;
    u32 wds[4];
    for (int e = 0; e < 4; ++e)
      wds[e] = (u32)f2bf(xs[e] * xs[e]) | ((u32)f2bf(-2.0f * xs[e]) << 16);
    v.x = wds[0]; v.y = wds[1]; v.z = wds[2]; v.w = wds[3];
    *(uint4*)(A + ((size_t)(t * 16 + cc) * 64 + l) * 8) = v;
  }
}

// ---------------------------------------------------------------------------
// Kernel 2: W weights (MFMA B layout via LDS transpose, coalesced 1 KB global
// stores) + per-comp const.
__global__ __launch_bounds__(256)
void prep_W(const float* __restrict__ mean, const float* __restrict__ stdd,
            u16* __restrict__ W, float* __restrict__ ck) {
  __shared__ u32 ldsW[4][16][268];
  int l = threadIdx.x & 63;
  int wv = threadIdx.x >> 6;
  int g = blockIdx.x * 4 + wv;        // 16-comp group 0..4095
  for (int p = 0; p < 16; ++p) {
    int comp = g * 16 + p;
    float4 m4 = *(const float4*)(mean + (size_t)comp * DDIM + l * 4);
    float4 s4 = *(const float4*)(stdd + (size_t)comp * DDIM + l * 4);
    float ms[4] = {m4.x, m4.y, m4.z, m4.w};
    float ss[4] = {s4.x, s4.y, s4.z, s4.w};
    u32 wds[4];
    float gsum = 0.f;
    for (int e = 0; e < 4; ++e) {
      float iv = 1.0f / (ss[e] * ss[e]);
      float miv = ms[e] * iv;
      wds[e] = (u32)f2bf(iv) | ((u32)f2bf(miv) << 16);
      gsum += -0.5f * ms[e] * miv - __logf(ss[e]);
    }
    for (int d = 1; d < 64; d <<= 1) gsum += __shfl_xor(gsum, d);
    if (l == 0) ck[comp] = gsum - LOG2PI_TERM;
    uint4 v; v.x = wds[0]; v.y = wds[1]; v.z = wds[2]; v.w = wds[3];
    *(uint4*)&ldsW[wv][p][l * 4] = v;
  }
  __syncthreads();
  for (int cc = 0; cc < 16; ++cc) {
    uint4 v = *(const uint4*)&ldsW[wv][l & 15][cc * 16 + ((l >> 4) << 2)];
    *(uint4*)(W + ((size_t)(g * 16 + cc) * 64 + l) * 8) = v;
  }
}

// ---------------------------------------------------------------------------
// Kernel 3: main GEMM + fused selection. Grid 1024 = 512 comp-blocks x 2
// row-halves; 256 thr (4 waves). Block owns 128 comps (wave: 32, two reg
// B-sets -> each A-frag LDS read feeds 2 MFMAs = the 8 MB/CU LDS floor).
// A streams via global_load_lds, 16-row double-buffered stages (32 KB).
// Scores are provably <= -235 (all-negative floats) => raw-bit unsigned-MIN
// is argmax of lp; top-2 merge across the 16 cols is pure-DPP (zero LDS ops).
__global__ __launch_bounds__(256, 2)
void main_gemm(const u16* __restrict__ A_ws, const u16* __restrict__ W_ws,
               const float* __restrict__ ck, u32* __restrict__ ckey) {
  __shared__ u16 Ash[2][16][512];      // 32 KB: [buf][cc][lane*8]
  __shared__ u32 wsel[2][16][9];       // [buf][row][4 waves x 2 + pad]
  int tid = threadIdx.x, l = tid & 63, w = tid >> 6;
  int nb = blockIdx.x & (NCB - 1);     // comp-block 0..511
  int rh = blockIdx.x >> 9;            // row half 0..1
  int g0 = nb * 8 + w * 2;             // two 16-comp groups per wave

  bf16x8 wfA[16], wfB[16];
#pragma unroll
  for (int cc = 0; cc < 16; ++cc) {
    wfA[cc] = *(const bf16x8*)(W_ws + ((size_t)(g0 * 16 + cc) * 64 + l) * 8);
    wfB[cc] = *(const bf16x8*)(W_ws + ((size_t)((g0 + 1) * 16 + cc) * 64 + l) * 8);
  }
  float mycA = ck[g0 * 16 + (l & 15)];
  float mycB = ck[(g0 + 1) * 16 + (l & 15)];
  u32 cA = (u32)(w * 32 + (l & 15));   // local comp id 0..127
  u32 cB = cA + 16;

  // stage S (1 m16-tile = 16 cells of 1 KB) into buf B; wave stages 4 cells
#define ISSUE(S, B)                                                           \
  {                                                                           \
    _Pragma("unroll")                                                         \
    for (int u = 0; u < 4; ++u) {                                             \
      int cell = w * 4 + u;                                                   \
      const u16* gsrc = A_ws +                                                \
        ((size_t)(rh * 32 + (S)) * 16 + cell) * 512 + (size_t)l * 8;          \
      __builtin_amdgcn_global_load_lds((gconst_u32*)gsrc,                     \
          (lds_u32*)&Ash[B][cell][0], 16, 0, 0);                              \
    }                                                                         \
  }

  // merge 8 wsel keys (min = best) -> 4 smallest for 16 rows; emit inverted
#define MERGE_EMIT(ST, B)                                                     \
  {                                                                           \
    int r = tid;                                                              \
    u32 top[4] = {~0u, ~0u, ~0u, ~0u};                                        \
    _Pragma("unroll")                                                         \
    for (int j = 0; j < 8; ++j) {                                             \
      u32 key = wsel[B][r][j];                                                \
      if (key < top[3]) {                                                     \
        top[3] = key;                                                         \
        for (int z = 3; z > 0 && top[z] < top[z - 1]; --z) {                  \
          u32 tt = top[z]; top[z] = top[z - 1]; top[z - 1] = tt;              \
        }                                                                     \
      }                                                                       \
    }                                                                         \
    int rowg = rh * 512 + (ST) * 16 + r;                                      \
    uint4 ov; ov.x = ~top[0]; ov.y = ~top[1]; ov.z = ~top[2]; ov.w = ~top[3]; \
    *(uint4*)&ckey[((size_t)rowg * NCB + nb) * 4] = ov;                       \
  }

  ISSUE(0, 0)
  for (int s = 0; s < 32; ++s) {
    int p = s & 1;
    __syncthreads();                   // buf p staged; wsel[p^1] complete
    if (s < 31) ISSUE(s + 1, p ^ 1)
    if (s > 0 && tid < 16) MERGE_EMIT(s - 1, p ^ 1)

    f32x4 aA = (f32x4){0.f, 0.f, 0.f, 0.f};
    f32x4 aB = (f32x4){0.f, 0.f, 0.f, 0.f};
#pragma unroll
    for (int cc = 0; cc < 16; ++cc) {
      bf16x8 a = *(const bf16x8*)(&Ash[p][cc][(size_t)l * 8]);
      aA = __builtin_amdgcn_mfma_f32_16x16x32_bf16(a, wfA[cc], aA, 0, 0, 0);
      aB = __builtin_amdgcn_mfma_f32_16x16x32_bf16(a, wfB[cc], aB, 0, 0, 0);
    }

    // per-row top-2 over wave's 32 comps; DPP rotation merge within 16 cols
#pragma unroll
    for (int i = 0; i < 4; ++i) {
      float sA = fmaf(aA[i], -0.5f, mycA);
      float sB = fmaf(aB[i], -0.5f, mycB);
      u32 kA = (__float_as_uint(sA) & 0xFFFFFF00u) | cA;
      u32 kB = (__float_as_uint(sB) & 0xFFFFFF00u) | cB;
      u32 m1 = kA < kB ? kA : kB;
      u32 m2 = kA < kB ? kB : kA;
#define DSTEP(CTRL)                                                           \
      {                                                                       \
        u32 o1 = (u32)__builtin_amdgcn_mov_dpp((int)m1, CTRL, 0xf, 0xf, false); \
        u32 o2 = (u32)__builtin_amdgcn_mov_dpp((int)m2, CTRL, 0xf, 0xf, false); \
        u32 lo = m1 < o1 ? m1 : o1;                                           \
        u32 hi = m1 < o1 ? o1 : m1;                                           \
        u32 mn = m2 < o2 ? m2 : o2;                                           \
        m2 = hi < mn ? hi : mn;                                               \
        m1 = lo;                                                              \
      }
      DSTEP(DPP_ROR1) DSTEP(DPP_ROR2) DSTEP(DPP_ROR4) DSTEP(DPP_ROR8)
#undef DSTEP
      int r = ((l >> 4) << 2) + i;
      if ((l & 15) == 0) wsel[p][r][w * 2] = m1;
      else if ((l & 15) == 1) wsel[p][r][w * 2 + 1] = m2;
    }
  }
  __syncthreads();
  if (tid < 16) MERGE_EMIT(31, 1)
#undef ISSUE
#undef MERGE_EMIT
}

// ---------------------------------------------------------------------------
// Kernel 4: per-row finalize. 2048 keys -> 4 parallel per-wave exact top-16
// via u32 ext-keys (lane+slot in low 9 bits) + DPP/shfl arg-max reduce; exact
// fp32 lp for 64; exact top-32 + softmax; weighted gather.
__global__ __launch_bounds__(256)
void finalize(const float* __restrict__ x, const float* __restrict__ mean,
              const float* __restrict__ stdd, const float* __restrict__ outs,
              const u32* __restrict__ ckey, float* __restrict__ out) {
  __shared__ u32 cksh[2048];
  __shared__ float xr[256];
  __shared__ float part[256];
  __shared__ int selk[64];
  __shared__ float ew[32];
  __shared__ int kf[32];
  __shared__ float invs_sh;
  int tid = threadIdx.x, l = tid & 63, v = tid >> 6;
  int row = blockIdx.x;

  for (int i = tid; i < 2048; i += 256)
    cksh[i] = ckey[(size_t)row * 2048 + i];
  xr[tid] = x[(size_t)row * DDIM + tid];
  __syncthreads();

  // 64-lane arg-max reduce on u32 (4 DPP rotations + 2 shfl)
#define REDUCE_MAX(m)                                                         \
  {                                                                           \
    u32 o;                                                                    \
    o = (u32)__builtin_amdgcn_mov_dpp((int)m, DPP_ROR1, 0xf, 0xf, false);     \
    m = m > o ? m : o;                                                        \
    o = (u32)__builtin_amdgcn_mov_dpp((int)m, DPP_ROR2, 0xf, 0xf, false);     \
    m = m > o ? m : o;                                                        \
    o = (u32)__builtin_amdgcn_mov_dpp((int)m, DPP_ROR4, 0xf, 0xf, false);     \
    m = m > o ? m : o;                                                        \
    o = (u32)__builtin_amdgcn_mov_dpp((int)m, DPP_ROR8, 0xf, 0xf, false);     \
    m = m > o ? m : o;                                                        \
    o = (u32)__shfl_xor((int)m, 16); m = m > o ? m : o;                       \
    o = (u32)__shfl_xor((int)m, 32); m = m > o ? m : o;                       \
  }

  {  // wave v: exact top-16 of its 512 cands
    u32 ext[8];
#pragma unroll
    for (int i = 0; i < 8; ++i) {
      int j = v * 512 + i * 64 + l;
      ext[i] = (cksh[j] & 0xFFFFFE00u) | ((u32)l << 3) | (u32)i;
    }
    // descending sort-8 network (odd-even merge, 19 comparators)
#define CSW(a, b) { if (ext[a] < ext[b]) { u32 t = ext[a]; ext[a] = ext[b]; ext[b] = t; } }
    CSW(0,1) CSW(2,3) CSW(4,5) CSW(6,7)
    CSW(0,2) CSW(1,3) CSW(4,6) CSW(5,7)
    CSW(1,2) CSW(5,6)
    CSW(0,4) CSW(1,5) CSW(2,6) CSW(3,7)
    CSW(2,4) CSW(3,5)
    CSW(1,2) CSW(3,4) CSW(5,6)
#undef CSW
    for (int it = 0; it < 16; ++it) {
      u32 m = ext[0];
      REDUCE_MAX(m)
      if (m == ext[0]) {               // unique winner pops its head
#pragma unroll
        for (int z = 0; z < 7; ++z) ext[z] = ext[z + 1];
        ext[7] = 0;
      }
      if (l == 0) {                    // decode winner from key bits
        int wl = (int)((m >> 3) & 63u), wi = (int)(m & 7u);
        int j = v * 512 + wi * 64 + wl;
        selk[v * 16 + it] = (int)((u32)(j >> 2) * 128u + (~cksh[j] & 0x7Fu));
      }
    }
  }
  __syncthreads();

  {  // exact fp32 lp for 64 cands, 4 threads each
    int j = tid >> 2, q = tid & 3;
    int k = selk[j];
    const float* mr = mean + (size_t)k * DDIM + q * 64;
    const float* sr = stdd + (size_t)k * DDIM + q * 64;
    float s2 = 0.f, ls = 0.f;
    for (int i = 0; i < 16; ++i) {
      float4 m4 = *(const float4*)(mr + 4 * i);
      float4 s4 = *(const float4*)(sr + 4 * i);
      float4 x4 = *(const float4*)(&xr[q * 64 + 4 * i]);
      { float is = 1.f / s4.x; float df = (x4.x - m4.x) * is; s2 += df * df; ls += __logf(s4.x); }
      { float is = 1.f / s4.y; float df = (x4.y - m4.y) * is; s2 += df * df; ls += __logf(s4.y); }
      { float is = 1.f / s4.z; float df = (x4.z - m4.z) * is; s2 += df * df; ls += __logf(s4.z); }
      { float is = 1.f / s4.w; float df = (x4.w - m4.w) * is; s2 += df * df; ls += __logf(s4.w); }
    }
    part[tid] = -0.5f * s2 - ls;
  }
  __syncthreads();

  if (tid < 64) {                      // exact top-32 + softmax (wave 0)
    float lp0 = part[l * 4] + part[l * 4 + 1] + part[l * 4 + 2] +
                part[l * 4 + 3] - LOG2PI_TERM;
    u32 ext = (fkey(lp0) & 0xFFFFFFC0u) | (u32)l;
    float maxlp = 0.f, ssum = 0.f;
    for (int it = 0; it < 32; ++it) {
      u32 m = ext;
      REDUCE_MAX(m)
      int j = (int)(m & 63u);
      u32 vb = m & 0xFFFFFFC0u;
      vb ^= (vb >> 31) ? 0x80000000u : 0xFFFFFFFFu;
      float lp = __uint_as_float(vb);
      if (it == 0) maxlp = lp;
      float e = __expf(lp - maxlp);
      ssum += e;
      if (l == 0) { ew[it] = e; kf[it] = selk[j]; }
      if (j == l) ext = 0;
    }
    if (l == 0) invs_sh = 1.0f / ssum;
  }
  __syncthreads();
#undef REDUCE_MAX

  {  // weighted gather: one output element per thread
    float a = 0.f;
    for (int i = 0; i < 32; ++i)
      a += ew[i] * outs[(size_t)kf[i] * ODIM + tid];
    out[(size_t)row * ODIM + tid] = a * invs_sh;
  }
}

// ---------------------------------------------------------------------------
extern "C" void kernel_launch(void* const* d_in, const int* in_sizes, int n_in,
                              void* d_out, int out_size, void* d_ws, size_t ws_size,
                              hipStream_t stream) {
  const float* x = (const float*)d_in[0];
  const float* mean = (const float*)d_in[1];
  const float* stdd = (const float*)d_in[2];
  const float* outs = (const float*)d_in[3];
  char* ws = (char*)d_ws;
  u16* A_ws = (u16*)(ws + WS_A);
  u16* W_ws = (u16*)(ws + WS_W);
  float* ck = (float*)(ws + WS_CONST);
  u32* ckey = (u32*)(ws + WS_KEY);

  prep_A<<<64, 256, 0, stream>>>(x, A_ws);
  prep_W<<<1024, 256, 0, stream>>>(mean, stdd, W_ws, ck);
  main_gemm<<<NBLK, 256, 0, stream>>>(A_ws, W_ws, ck, ckey);
  finalize<<<BROWS, 256, 0, stream>>>(x, mean, stdd, outs, ckey,
                                      (float*)d_out);
}

// Round 5
// 415.755 us; speedup vs baseline: 2.3964x; 1.0093x over previous
//
#include <hip/hip_runtime.h>
#include <stdint.h>

// Problem constants
#define KCOMP 65536
#define DDIM  256
#define ODIM  256
#define BROWS 1024
#define NCB   512            // comp-blocks: KCOMP / 128 comps per block
#define NBLK  1024           // main grid: NCB * 2 row-halves
#define LOG2PI_TERM 235.2482645f   // 0.5 * D * ln(2*pi)

typedef float f32x4 __attribute__((ext_vector_type(4)));
typedef __bf16 bf16x8 __attribute__((ext_vector_type(8)));
typedef unsigned int u32;
typedef unsigned long long u64;
typedef unsigned short u16;

typedef __attribute__((address_space(1))) const u32 gconst_u32;
typedef __attribute__((address_space(3))) u32 lds_u32;

__device__ __forceinline__ u16 f2bf(float f) {
  u32 b = __float_as_uint(f);
  b += 0x7FFFu + ((b >> 16) & 1u);
  return (u16)(b >> 16);
}
// monotone float->u32 key (finalize only — main_gemm scores are all-negative
// so raw bits with unsigned-MIN are already order-correct)
__device__ __forceinline__ u32 fkey(float f) {
  u32 b = __float_as_uint(f);
  return b ^ ((b >> 31) ? 0xFFFFFFFFu : 0x80000000u);
}

// DPP row_ror:n (rotate within 16-lane rows) — pure-VALU lane exchange,
// keeps selection OFF the LDS pipe (round-3 lesson).
#define DPP_ROR1 0x121
#define DPP_ROR2 0x122
#define DPP_ROR4 0x124
#define DPP_ROR8 0x128

// ws layout (bytes). Total ~9 MB (round-4's 64 MB W buffer is fused away).
#define WS_A     0                          // 1 MB  A frag-linear [64 tile][16 cc][64 lane][16B]
#define WS_KEY   (1u << 20)                 // 8 MB  cand keys [1024 row][512 cb][4]

// ---------------------------------------------------------------------------
// Kernel 1: A features. kappa=2d -> x_d^2 ; kappa=2d+1 -> -2 x_d (MFMA A layout).
__global__ void prep_A(const float* __restrict__ x, u16* __restrict__ A) {
  int l = threadIdx.x & 63;
  int wv = threadIdx.x >> 6;
  int t = blockIdx.x;                 // m16 tile 0..63
  int row = t * 16 + (l & 15);
  for (int u = 0; u < 4; ++u) {
    int cc = wv * 4 + u;              // 0..15
    int d0 = cc * 16 + ((l >> 4) << 2);
    float4 xv = *(const float4*)(x + (size_t)row * DDIM + d0);
    float xs[4] = {xv.x, xv.y, xv.z, xv.w};
    uint4 v;
    u32 wds[4];
    for (int e = 0; e < 4; ++e)
      wds[e] = (u32)f2bf(xs[e] * xs[e]) | ((u32)f2bf(-2.0f * xs[e]) << 16);
    v.x = wds[0]; v.y = wds[1]; v.z = wds[2]; v.w = wds[3];
    *(uint4*)(A + ((size_t)(t * 16 + cc) * 64 + l) * 8) = v;
  }
}

// ---------------------------------------------------------------------------
// Kernel 2: main GEMM + fused W-conversion + fused selection.
// Grid 1024 = 512 comp-blocks x 2 row-halves; 256 thr (4 waves).
// PROLOGUE: each wave converts its own 32 comps of (mean,stdd) fp32 ->
//   bf16 (iv|miv) MFMA B-frags in registers, via a per-wave LDS transpose
//   (16.6 KB, unioned with the A-staging buffer); per-comp const ck is
//   reduced in-register (2 shfls). This deletes round-4's prep_W kernel,
//   its 64 MB store and 64 MB frag re-read.
// MAIN LOOP: A streams via global_load_lds, 32-row double-buffered stages
//   (16 barriers/block; 2 independent A-tiles = 2x MFMA ILP per stage).
//   Scores provably <= -235 => raw-bit unsigned-MIN selection, DPP top-2
//   per wave, per-stage merge 8 -> top-4 per row, one uint4 store per row.
__global__ __launch_bounds__(256, 2)
void main_gemm(const u16* __restrict__ A_ws, const float* __restrict__ mean,
               const float* __restrict__ stdd, u32* __restrict__ ckey) {
  // union: [0,66560) = per-wave conversion scratch (4 x 16640 B) in prologue,
  //        [0,65536) = A double-buffer (2 bufs x 32 cells x 1 KB) in main loop
  __shared__ __align__(16) char lds_raw[66560];
  __shared__ u32 wsel[2][32][9];       // [buf][row][4 waves x 2 + pad]
  int tid = threadIdx.x, l = tid & 63, w = tid >> 6;
  int nb = blockIdx.x & (NCB - 1);     // comp-block 0..511
  int rh = blockIdx.x >> 9;            // row half 0..1
  int g0 = nb * 8 + w * 2;             // two 16-comp groups per wave
  int p = l & 15, q = l >> 4;

  // ---- prologue: build wf[2][16] B-frags + myc[2] from mean/stdd ----
  bf16x8 wf[2][16];
  float myc[2];
  {
    u32* scr = (u32*)(lds_raw + w * 16640);  // [16 comps][260 dwords] padded
#pragma unroll
    for (int gs = 0; gs < 2; ++gs) {
      int comp = (g0 + gs) * 16 + p;
      const float* mrow = mean + (size_t)comp * DDIM + q * 64;
      const float* srow = stdd + (size_t)comp * DDIM + q * 64;
      float gsum = 0.f;
#pragma unroll
      for (int i = 0; i < 16; ++i) {
        float4 m4 = *(const float4*)(mrow + 4 * i);
        float4 s4 = *(const float4*)(srow + 4 * i);
        float ms[4] = {m4.x, m4.y, m4.z, m4.w};
        float ss[4] = {s4.x, s4.y, s4.z, s4.w};
        u32 wd[4];
#pragma unroll
        for (int e = 0; e < 4; ++e) {
          float iv = __builtin_amdgcn_rcpf(ss[e] * ss[e]);
          float miv = ms[e] * iv;
          wd[e] = (u32)f2bf(iv) | ((u32)f2bf(miv) << 16);
          gsum -= 0.5f * ms[e] * miv + __logf(ss[e]);
        }
        uint4 v; v.x = wd[0]; v.y = wd[1]; v.z = wd[2]; v.w = wd[3];
        *(uint4*)(scr + p * 260 + q * 64 + i * 4) = v;   // [comp][dim] packed
      }
      gsum += __shfl_xor(gsum, 16);    // sum the 4 quarter-partials of comp p
      gsum += __shfl_xor(gsum, 32);
      myc[gs] = gsum - LOG2PI_TERM;
      // frag read (wave-local; in-order LDS): lane l -> comp p, dims cc*16+q*4
#pragma unroll
      for (int cc = 0; cc < 16; ++cc)
        wf[gs][cc] = *(const bf16x8*)(scr + p * 260 + cc * 16 + q * 4);
    }
  }
  __syncthreads();                     // scratch region now reused as Ash

  u32 cA = (u32)(w * 32 + p);          // local comp ids 0..127
  u32 cB = cA + 16;
#define ASHP(B, CELL) (lds_raw + ((size_t)(B) * 32 + (CELL)) * 1024)

  // stage S (2 m16-tiles = 32 cells of 1 KB) into buf B; wave stages 8 cells
#define ISSUE(S, B)                                                           \
  {                                                                           \
    _Pragma("unroll")                                                         \
    for (int u = 0; u < 8; ++u) {                                             \
      int cell = w * 8 + u;                                                   \
      const u16* gsrc = A_ws +                                                \
        ((size_t)(rh * 32 + (S) * 2 + (cell >> 4)) * 16 + (cell & 15)) * 512  \
        + (size_t)l * 8;                                                      \
      __builtin_amdgcn_global_load_lds((gconst_u32*)gsrc,                     \
          (lds_u32*)ASHP(B, cell), 16, 0, 0);                                 \
    }                                                                         \
  }

  // merge 8 wsel keys (min = best) -> 4 smallest for 32 rows; emit inverted
#define MERGE_EMIT(ST, B)                                                     \
  {                                                                           \
    int r = tid;                                                              \
    u32 top[4] = {~0u, ~0u, ~0u, ~0u};                                        \
    _Pragma("unroll")                                                         \
    for (int j = 0; j < 8; ++j) {                                             \
      u32 key = wsel[B][r][j];                                                \
      if (key < top[3]) {                                                     \
        top[3] = key;                                                         \
        for (int z = 3; z > 0 && top[z] < top[z - 1]; --z) {                  \
          u32 tt = top[z]; top[z] = top[z - 1]; top[z - 1] = tt;              \
        }                                                                     \
      }                                                                       \
    }                                                                         \
    int rowg = rh * 512 + (ST) * 32 + r;                                      \
    uint4 ov; ov.x = ~top[0]; ov.y = ~top[1]; ov.z = ~top[2]; ov.w = ~top[3]; \
    *(uint4*)&ckey[((size_t)rowg * NCB + nb) * 4] = ov;                       \
  }

  ISSUE(0, 0)
  for (int s = 0; s < 16; ++s) {
    int pb = s & 1;
    __syncthreads();                   // buf pb staged; wsel[pb^1] complete
    if (s < 15) ISSUE(s + 1, pb ^ 1)
    if (s > 0 && tid < 32) MERGE_EMIT(s - 1, pb ^ 1)

    f32x4 ac[2][2];                    // [tile][comp-set]
#pragma unroll
    for (int t = 0; t < 2; ++t) {
      ac[t][0] = (f32x4){0.f, 0.f, 0.f, 0.f};
      ac[t][1] = (f32x4){0.f, 0.f, 0.f, 0.f};
    }
#pragma unroll
    for (int cc = 0; cc < 16; ++cc) {
      bf16x8 a0 = *(const bf16x8*)(ASHP(pb, cc) + (size_t)l * 16);
      bf16x8 a1 = *(const bf16x8*)(ASHP(pb, 16 + cc) + (size_t)l * 16);
      ac[0][0] = __builtin_amdgcn_mfma_f32_16x16x32_bf16(a0, wf[0][cc], ac[0][0], 0, 0, 0);
      ac[0][1] = __builtin_amdgcn_mfma_f32_16x16x32_bf16(a0, wf[1][cc], ac[0][1], 0, 0, 0);
      ac[1][0] = __builtin_amdgcn_mfma_f32_16x16x32_bf16(a1, wf[0][cc], ac[1][0], 0, 0, 0);
      ac[1][1] = __builtin_amdgcn_mfma_f32_16x16x32_bf16(a1, wf[1][cc], ac[1][1], 0, 0, 0);
    }

    // per-row top-2 over wave's 32 comps; DPP merge within 16 cols
#pragma unroll
    for (int t = 0; t < 2; ++t)
#pragma unroll
      for (int i = 0; i < 4; ++i) {
        float sA = fmaf(ac[t][0][i], -0.5f, myc[0]);
        float sB = fmaf(ac[t][1][i], -0.5f, myc[1]);
        u32 kA = (__float_as_uint(sA) & 0xFFFFFF00u) | cA;
        u32 kB = (__float_as_uint(sB) & 0xFFFFFF00u) | cB;
        u32 m1 = kA < kB ? kA : kB;
        u32 m2 = kA < kB ? kB : kA;
#define DSTEP(CTRL)                                                           \
        {                                                                     \
          u32 o1 = (u32)__builtin_amdgcn_mov_dpp((int)m1, CTRL, 0xf, 0xf, false); \
          u32 o2 = (u32)__builtin_amdgcn_mov_dpp((int)m2, CTRL, 0xf, 0xf, false); \
          u32 lo = m1 < o1 ? m1 : o1;                                         \
          u32 hi = m1 < o1 ? o1 : m1;                                         \
          u32 mn = m2 < o2 ? m2 : o2;                                         \
          m2 = hi < mn ? hi : mn;                                             \
          m1 = lo;                                                            \
        }
        DSTEP(DPP_ROR1) DSTEP(DPP_ROR2) DSTEP(DPP_ROR4) DSTEP(DPP_ROR8)
#undef DSTEP
        int r = t * 16 + q * 4 + i;
        if (p == 0) wsel[pb][r][w * 2] = m1;
        else if (p == 1) wsel[pb][r][w * 2 + 1] = m2;
      }
  }
  __syncthreads();
  if (tid < 32) MERGE_EMIT(15, 1)
#undef ISSUE
#undef MERGE_EMIT
#undef ASHP
}

// ---------------------------------------------------------------------------
// Kernel 3: per-row finalize. 2048 keys -> 4 parallel per-wave exact top-16
// via u32 ext-keys + DPP/shfl arg-max; exact fp32 lp for 64; exact top-32 +
// softmax; weighted gather.
__global__ __launch_bounds__(256)
void finalize(const float* __restrict__ x, const float* __restrict__ mean,
              const float* __restrict__ stdd, const float* __restrict__ outs,
              const u32* __restrict__ ckey, float* __restrict__ out) {
  __shared__ u32 cksh[2048];
  __shared__ float xr[256];
  __shared__ float part[256];
  __shared__ int selk[64];
  __shared__ float ew[32];
  __shared__ int kf[32];
  __shared__ float invs_sh;
  int tid = threadIdx.x, l = tid & 63, v = tid >> 6;
  int row = blockIdx.x;

  for (int i = tid; i < 2048; i += 256)
    cksh[i] = ckey[(size_t)row * 2048 + i];
  xr[tid] = x[(size_t)row * DDIM + tid];
  __syncthreads();

  // 64-lane max reduce on u32 (4 DPP rotations + 2 shfl)
#define REDUCE_MAX(m)                                                         \
  {                                                                           \
    u32 o;                                                                    \
    o = (u32)__builtin_amdgcn_mov_dpp((int)m, DPP_ROR1, 0xf, 0xf, false);     \
    m = m > o ? m : o;                                                        \
    o = (u32)__builtin_amdgcn_mov_dpp((int)m, DPP_ROR2, 0xf, 0xf, false);     \
    m = m > o ? m : o;                                                        \
    o = (u32)__builtin_amdgcn_mov_dpp((int)m, DPP_ROR4, 0xf, 0xf, false);     \
    m = m > o ? m : o;                                                        \
    o = (u32)__builtin_amdgcn_mov_dpp((int)m, DPP_ROR8, 0xf, 0xf, false);     \
    m = m > o ? m : o;                                                        \
    o = (u32)__shfl_xor((int)m, 16); m = m > o ? m : o;                       \
    o = (u32)__shfl_xor((int)m, 32); m = m > o ? m : o;                       \
  }

  {  // wave v: exact top-16 of its 512 cands
    u32 ext[8];
#pragma unroll
    for (int i = 0; i < 8; ++i) {
      int j = v * 512 + i * 64 + l;
      ext[i] = (cksh[j] & 0xFFFFFE00u) | ((u32)l << 3) | (u32)i;
    }
#define CSW(a, b) { if (ext[a] < ext[b]) { u32 t = ext[a]; ext[a] = ext[b]; ext[b] = t; } }
    CSW(0,1) CSW(2,3) CSW(4,5) CSW(6,7)
    CSW(0,2) CSW(1,3) CSW(4,6) CSW(5,7)
    CSW(1,2) CSW(5,6)
    CSW(0,4) CSW(1,5) CSW(2,6) CSW(3,7)
    CSW(2,4) CSW(3,5)
    CSW(1,2) CSW(3,4) CSW(5,6)
#undef CSW
    for (int it = 0; it < 16; ++it) {
      u32 m = ext[0];
      REDUCE_MAX(m)
      if (m == ext[0]) {
#pragma unroll
        for (int z = 0; z < 7; ++z) ext[z] = ext[z + 1];
        ext[7] = 0;
      }
      if (l == 0) {
        int wl = (int)((m >> 3) & 63u), wi = (int)(m & 7u);
        int j = v * 512 + wi * 64 + wl;
        selk[v * 16 + it] = (int)((u32)(j >> 2) * 128u + (~cksh[j] & 0x7Fu));
      }
    }
  }
  __syncthreads();

  {  // exact fp32 lp for 64 cands, 4 threads each
    int j = tid >> 2, qq = tid & 3;
    int k = selk[j];
    const float* mr = mean + (size_t)k * DDIM + qq * 64;
    const float* sr = stdd + (size_t)k * DDIM + qq * 64;
    float s2 = 0.f, ls = 0.f;
    for (int i = 0; i < 16; ++i) {
      float4 m4 = *(const float4*)(mr + 4 * i);
      float4 s4 = *(const float4*)(sr + 4 * i);
      float4 x4 = *(const float4*)(&xr[qq * 64 + 4 * i]);
      { float is = 1.f / s4.x; float df = (x4.x - m4.x) * is; s2 += df * df; ls += __logf(s4.x); }
      { float is = 1.f / s4.y; float df = (x4.y - m4.y) * is; s2 += df * df; ls += __logf(s4.y); }
      { float is = 1.f / s4.z; float df = (x4.z - m4.z) * is; s2 += df * df; ls += __logf(s4.z); }
      { float is = 1.f / s4.w; float df = (x4.w - m4.w) * is; s2 += df * df; ls += __logf(s4.w); }
    }
    part[tid] = -0.5f * s2 - ls;
  }
  __syncthreads();

  if (tid < 64) {                      // exact top-32 + softmax (wave 0)
    float lp0 = part[l * 4] + part[l * 4 + 1] + part[l * 4 + 2] +
                part[l * 4 + 3] - LOG2PI_TERM;
    u32 ext = (fkey(lp0) & 0xFFFFFFC0u) | (u32)l;
    float maxlp = 0.f, ssum = 0.f;
    for (int it = 0; it < 32; ++it) {
      u32 m = ext;
      REDUCE_MAX(m)
      int j = (int)(m & 63u);
      u32 vb = m & 0xFFFFFFC0u;
      vb ^= (vb >> 31) ? 0x80000000u : 0xFFFFFFFFu;
      float lp = __uint_as_float(vb);
      if (it == 0) maxlp = lp;
      float e = __expf(lp - maxlp);
      ssum += e;
      if (l == 0) { ew[it] = e; kf[it] = selk[j]; }
      if (j == l) ext = 0;
    }
    if (l == 0) invs_sh = 1.0f / ssum;
  }
  __syncthreads();
#undef REDUCE_MAX

  {  // weighted gather: one output element per thread
    float a = 0.f;
    for (int i = 0; i < 32; ++i)
      a += ew[i] * outs[(size_t)kf[i] * ODIM + tid];
    out[(size_t)row * ODIM + tid] = a * invs_sh;
  }
}

// ---------------------------------------------------------------------------
extern "C" void kernel_launch(void* const* d_in, const int* in_sizes, int n_in,
                              void* d_out, int out_size, void* d_ws, size_t ws_size,
                              hipStream_t stream) {
  const float* x = (const float*)d_in[0];
  const float* mean = (const float*)d_in[1];
  const float* stdd = (const float*)d_in[2];
  const float* outs = (const float*)d_in[3];
  char* ws = (char*)d_ws;
  u16* A_ws = (u16*)(ws + WS_A);
  u32* ckey = (u32*)(ws + WS_KEY);

  prep_A<<<64, 256, 0, stream>>>(x, A_ws);
  main_gemm<<<NBLK, 256, 0, stream>>>(A_ws, mean, stdd, ckey);
  finalize<<<BROWS, 256, 0, stream>>>(x, mean, stdd, outs, ckey,
                                      (float*)d_out);
}

// Round 6
// 374.989 us; speedup vs baseline: 2.6570x; 1.1087x over previous
//
#include <hip/hip_runtime.h>
#include <stdint.h>

// Problem constants
#define KCOMP 65536
#define DDIM  256
#define ODIM  256
#define BROWS 1024
#define NCB   512            // comp-blocks: KCOMP / 128 comps per block
#define NBLK  512            // main grid: one block per comp-block (no row split)
#define LOG2PI_TERM 235.2482645f   // 0.5 * D * ln(2*pi)

typedef float f32x4 __attribute__((ext_vector_type(4)));
typedef __bf16 bf16x8 __attribute__((ext_vector_type(8)));
typedef unsigned int u32;
typedef unsigned long long u64;
typedef unsigned short u16;

typedef __attribute__((address_space(1))) const u32 gconst_u32;
typedef __attribute__((address_space(3))) u32 lds_u32;

__device__ __forceinline__ u16 f2bf(float f) {
  u32 b = __float_as_uint(f);
  b += 0x7FFFu + ((b >> 16) & 1u);
  return (u16)(b >> 16);
}
// monotone float->u32 key (finalize only — main_gemm scores are all-negative
// so raw bits with unsigned-MIN are already order-correct)
__device__ __forceinline__ u32 fkey(float f) {
  u32 b = __float_as_uint(f);
  return b ^ ((b >> 31) ? 0xFFFFFFFFu : 0x80000000u);
}

// DPP row_ror:n (rotate within 16-lane rows) — pure-VALU lane exchange,
// keeps selection OFF the LDS pipe (round-3 lesson).
#define DPP_ROR1 0x121
#define DPP_ROR2 0x122
#define DPP_ROR4 0x124
#define DPP_ROR8 0x128

// ws layout (bytes). Total ~9 MB.
#define WS_A     0                          // 1 MB  A frag-linear [64 tile][16 cc][64 lane][16B]
#define WS_KEY   (1u << 20)                 // 8 MB  cand keys [1024 row][512 cb][4]

// ---------------------------------------------------------------------------
// Kernel 1: A features. kappa=2d -> x_d^2 ; kappa=2d+1 -> -2 x_d (MFMA A layout).
__global__ void prep_A(const float* __restrict__ x, u16* __restrict__ A) {
  int l = threadIdx.x & 63;
  int wv = threadIdx.x >> 6;
  int t = blockIdx.x;                 // m16 tile 0..63
  int row = t * 16 + (l & 15);
  for (int u = 0; u < 4; ++u) {
    int cc = wv * 4 + u;              // 0..15
    int d0 = cc * 16 + ((l >> 4) << 2);
    float4 xv = *(const float4*)(x + (size_t)row * DDIM + d0);
    float xs[4] = {xv.x, xv.y, xv.z, xv.w};
    uint4 v;
    u32 wds[4];
    for (int e = 0; e < 4; ++e)
      wds[e] = (u32)f2bf(xs[e] * xs[e]) | ((u32)f2bf(-2.0f * xs[e]) << 16);
    v.x = wds[0]; v.y = wds[1]; v.z = wds[2]; v.w = wds[3];
    *(uint4*)(A + ((size_t)(t * 16 + cc) * 64 + l) * 8) = v;
  }
}

// ---------------------------------------------------------------------------
// Kernel 2: main GEMM + fused W-conversion + fused selection.
// Grid 512 = one block per 128 comps; block sweeps ALL 1024 rows (round-5's
// row-half split made every block's 256 KB mean/stdd prologue fetch happen
// twice -> 487 MB FETCH, ~100 us of pure HBM re-read; now fetched once).
// PROLOGUE: wave converts its 32 comps fp32 -> bf16 (iv|miv) B-frags in regs
//   via per-wave LDS transpose (unioned with A buffer); ck reduced via shfl.
// MAIN LOOP: A streams via global_load_lds, 32 double-buffered 32-row stages.
//   Raw-bit unsigned-MIN selection (scores provably <= -235), DPP top-2 per
//   wave, per-stage merge 8 -> top-4 per row, one uint4 store per row.
__global__ __launch_bounds__(256, 2)
void main_gemm(const u16* __restrict__ A_ws, const float* __restrict__ mean,
               const float* __restrict__ stdd, u32* __restrict__ ckey) {
  // union: [0,66560) = per-wave conversion scratch (4 x 16640 B) in prologue,
  //        [0,65536) = A double-buffer (2 bufs x 32 cells x 1 KB) in main loop
  __shared__ __align__(16) char lds_raw[66560];
  __shared__ u32 wsel[2][32][9];       // [buf][row][4 waves x 2 + pad]
  int tid = threadIdx.x, l = tid & 63, w = tid >> 6;
  int nb = blockIdx.x;                 // comp-block 0..511
  int g0 = nb * 8 + w * 2;             // two 16-comp groups per wave
  int p = l & 15, q = l >> 4;

  // ---- prologue: build wf[2][16] B-frags + myc[2] from mean/stdd ----
  bf16x8 wf[2][16];
  float myc[2];
  {
    u32* scr = (u32*)(lds_raw + w * 16640);  // [16 comps][260 dwords] padded
#pragma unroll
    for (int gs = 0; gs < 2; ++gs) {
      int comp = (g0 + gs) * 16 + p;
      const float* mrow = mean + (size_t)comp * DDIM + q * 64;
      const float* srow = stdd + (size_t)comp * DDIM + q * 64;
      float gsum = 0.f;
#pragma unroll
      for (int i = 0; i < 16; ++i) {
        float4 m4 = *(const float4*)(mrow + 4 * i);
        float4 s4 = *(const float4*)(srow + 4 * i);
        float ms[4] = {m4.x, m4.y, m4.z, m4.w};
        float ss[4] = {s4.x, s4.y, s4.z, s4.w};
        u32 wd[4];
#pragma unroll
        for (int e = 0; e < 4; ++e) {
          float iv = __builtin_amdgcn_rcpf(ss[e] * ss[e]);
          float miv = ms[e] * iv;
          wd[e] = (u32)f2bf(iv) | ((u32)f2bf(miv) << 16);
          gsum -= 0.5f * ms[e] * miv + __logf(ss[e]);
        }
        uint4 v; v.x = wd[0]; v.y = wd[1]; v.z = wd[2]; v.w = wd[3];
        *(uint4*)(scr + p * 260 + q * 64 + i * 4) = v;   // [comp][dim] packed
      }
      gsum += __shfl_xor(gsum, 16);    // sum the 4 quarter-partials of comp p
      gsum += __shfl_xor(gsum, 32);
      myc[gs] = gsum - LOG2PI_TERM;
      // frag read (wave-local; in-order LDS): lane l -> comp p, dims cc*16+q*4
#pragma unroll
      for (int cc = 0; cc < 16; ++cc)
        wf[gs][cc] = *(const bf16x8*)(scr + p * 260 + cc * 16 + q * 4);
    }
  }
  __syncthreads();                     // scratch region now reused as Ash

  u32 cA = (u32)(w * 32 + p);          // local comp ids 0..127
  u32 cB = cA + 16;
#define ASHP(B, CELL) (lds_raw + ((size_t)(B) * 32 + (CELL)) * 1024)

  // stage S (2 m16-tiles = 32 cells of 1 KB) into buf B; wave stages 8 cells
#define ISSUE(S, B)                                                           \
  {                                                                           \
    _Pragma("unroll")                                                         \
    for (int u = 0; u < 8; ++u) {                                             \
      int cell = w * 8 + u;                                                   \
      const u16* gsrc = A_ws +                                                \
        ((size_t)((S) * 2 + (cell >> 4)) * 16 + (cell & 15)) * 512            \
        + (size_t)l * 8;                                                      \
      __builtin_amdgcn_global_load_lds((gconst_u32*)gsrc,                     \
          (lds_u32*)ASHP(B, cell), 16, 0, 0);                                 \
    }                                                                         \
  }

  // merge 8 wsel keys (min = best) -> 4 smallest for 32 rows; emit inverted
#define MERGE_EMIT(ST, B)                                                     \
  {                                                                           \
    int r = tid;                                                              \
    u32 top[4] = {~0u, ~0u, ~0u, ~0u};                                        \
    _Pragma("unroll")                                                         \
    for (int j = 0; j < 8; ++j) {                                             \
      u32 key = wsel[B][r][j];                                                \
      if (key < top[3]) {                                                     \
        top[3] = key;                                                         \
        for (int z = 3; z > 0 && top[z] < top[z - 1]; --z) {                  \
          u32 tt = top[z]; top[z] = top[z - 1]; top[z - 1] = tt;              \
        }                                                                     \
      }                                                                       \
    }                                                                         \
    int rowg = (ST) * 32 + r;                                                 \
    uint4 ov; ov.x = ~top[0]; ov.y = ~top[1]; ov.z = ~top[2]; ov.w = ~top[3]; \
    *(uint4*)&ckey[((size_t)rowg * NCB + nb) * 4] = ov;                       \
  }

  ISSUE(0, 0)
  for (int s = 0; s < 32; ++s) {
    int pb = s & 1;
    __syncthreads();                   // buf pb staged; wsel[pb^1] complete
    if (s < 31) ISSUE(s + 1, pb ^ 1)
    if (s > 0 && tid < 32) MERGE_EMIT(s - 1, pb ^ 1)

    f32x4 ac[2][2];                    // [tile][comp-set]
#pragma unroll
    for (int t = 0; t < 2; ++t) {
      ac[t][0] = (f32x4){0.f, 0.f, 0.f, 0.f};
      ac[t][1] = (f32x4){0.f, 0.f, 0.f, 0.f};
    }
#pragma unroll
    for (int cc = 0; cc < 16; ++cc) {
      bf16x8 a0 = *(const bf16x8*)(ASHP(pb, cc) + (size_t)l * 16);
      bf16x8 a1 = *(const bf16x8*)(ASHP(pb, 16 + cc) + (size_t)l * 16);
      ac[0][0] = __builtin_amdgcn_mfma_f32_16x16x32_bf16(a0, wf[0][cc], ac[0][0], 0, 0, 0);
      ac[0][1] = __builtin_amdgcn_mfma_f32_16x16x32_bf16(a0, wf[1][cc], ac[0][1], 0, 0, 0);
      ac[1][0] = __builtin_amdgcn_mfma_f32_16x16x32_bf16(a1, wf[0][cc], ac[1][0], 0, 0, 0);
      ac[1][1] = __builtin_amdgcn_mfma_f32_16x16x32_bf16(a1, wf[1][cc], ac[1][1], 0, 0, 0);
    }

    // per-row top-2 over wave's 32 comps; DPP merge within 16 cols
#pragma unroll
    for (int t = 0; t < 2; ++t)
#pragma unroll
      for (int i = 0; i < 4; ++i) {
        float sA = fmaf(ac[t][0][i], -0.5f, myc[0]);
        float sB = fmaf(ac[t][1][i], -0.5f, myc[1]);
        u32 kA = (__float_as_uint(sA) & 0xFFFFFF00u) | cA;
        u32 kB = (__float_as_uint(sB) & 0xFFFFFF00u) | cB;
        u32 m1 = kA < kB ? kA : kB;
        u32 m2 = kA < kB ? kB : kA;
#define DSTEP(CTRL)                                                           \
        {                                                                     \
          u32 o1 = (u32)__builtin_amdgcn_mov_dpp((int)m1, CTRL, 0xf, 0xf, false); \
          u32 o2 = (u32)__builtin_amdgcn_mov_dpp((int)m2, CTRL, 0xf, 0xf, false); \
          u32 lo = m1 < o1 ? m1 : o1;                                         \
          u32 hi = m1 < o1 ? o1 : m1;                                         \
          u32 mn = m2 < o2 ? m2 : o2;                                         \
          m2 = hi < mn ? hi : mn;                                             \
          m1 = lo;                                                            \
        }
        DSTEP(DPP_ROR1) DSTEP(DPP_ROR2) DSTEP(DPP_ROR4) DSTEP(DPP_ROR8)
#undef DSTEP
        int r = t * 16 + q * 4 + i;
        if (p == 0) wsel[pb][r][w * 2] = m1;
        else if (p == 1) wsel[pb][r][w * 2 + 1] = m2;
      }
  }
  __syncthreads();
  if (tid < 32) MERGE_EMIT(31, 1)
#undef ISSUE
#undef MERGE_EMIT
#undef ASHP
}

// ---------------------------------------------------------------------------
// Kernel 3: per-row finalize. 2048 keys -> 4 parallel per-wave exact top-16
// via u32 ext-keys + DPP/shfl arg-max; exact fp32 lp for 64; exact top-32 +
// softmax; weighted gather.
__global__ __launch_bounds__(256)
void finalize(const float* __restrict__ x, const float* __restrict__ mean,
              const float* __restrict__ stdd, const float* __restrict__ outs,
              const u32* __restrict__ ckey, float* __restrict__ out) {
  __shared__ u32 cksh[2048];
  __shared__ float xr[256];
  __shared__ float part[256];
  __shared__ int selk[64];
  __shared__ float ew[32];
  __shared__ int kf[32];
  __shared__ float invs_sh;
  int tid = threadIdx.x, l = tid & 63, v = tid >> 6;
  int row = blockIdx.x;

  for (int i = tid; i < 2048; i += 256)
    cksh[i] = ckey[(size_t)row * 2048 + i];
  xr[tid] = x[(size_t)row * DDIM + tid];
  __syncthreads();

  // 64-lane max reduce on u32 (4 DPP rotations + 2 shfl)
#define REDUCE_MAX(m)                                                         \
  {                                                                           \
    u32 o;                                                                    \
    o = (u32)__builtin_amdgcn_mov_dpp((int)m, DPP_ROR1, 0xf, 0xf, false);     \
    m = m > o ? m : o;                                                        \
    o = (u32)__builtin_amdgcn_mov_dpp((int)m, DPP_ROR2, 0xf, 0xf, false);     \
    m = m > o ? m : o;                                                        \
    o = (u32)__builtin_amdgcn_mov_dpp((int)m, DPP_ROR4, 0xf, 0xf, false);     \
    m = m > o ? m : o;                                                        \
    o = (u32)__builtin_amdgcn_mov_dpp((int)m, DPP_ROR8, 0xf, 0xf, false);     \
    m = m > o ? m : o;                                                        \
    o = (u32)__shfl_xor((int)m, 16); m = m > o ? m : o;                       \
    o = (u32)__shfl_xor((int)m, 32); m = m > o ? m : o;                       \
  }

  {  // wave v: exact top-16 of its 512 cands
    u32 ext[8];
#pragma unroll
    for (int i = 0; i < 8; ++i) {
      int j = v * 512 + i * 64 + l;
      ext[i] = (cksh[j] & 0xFFFFFE00u) | ((u32)l << 3) | (u32)i;
    }
#define CSW(a, b) { if (ext[a] < ext[b]) { u32 t = ext[a]; ext[a] = ext[b]; ext[b] = t; } }
    CSW(0,1) CSW(2,3) CSW(4,5) CSW(6,7)
    CSW(0,2) CSW(1,3) CSW(4,6) CSW(5,7)
    CSW(1,2) CSW(5,6)
    CSW(0,4) CSW(1,5) CSW(2,6) CSW(3,7)
    CSW(2,4) CSW(3,5)
    CSW(1,2) CSW(3,4) CSW(5,6)
#undef CSW
    for (int it = 0; it < 16; ++it) {
      u32 m = ext[0];
      REDUCE_MAX(m)
      if (m == ext[0]) {
#pragma unroll
        for (int z = 0; z < 7; ++z) ext[z] = ext[z + 1];
        ext[7] = 0;
      }
      if (l == 0) {
        int wl = (int)((m >> 3) & 63u), wi = (int)(m & 7u);
        int j = v * 512 + wi * 64 + wl;
        selk[v * 16 + it] = (int)((u32)(j >> 2) * 128u + (~cksh[j] & 0x7Fu));
      }
    }
  }
  __syncthreads();

  {  // exact fp32 lp for 64 cands, 4 threads each
    int j = tid >> 2, qq = tid & 3;
    int k = selk[j];
    const float* mr = mean + (size_t)k * DDIM + qq * 64;
    const float* sr = stdd + (size_t)k * DDIM + qq * 64;
    float s2 = 0.f, ls = 0.f;
    for (int i = 0; i < 16; ++i) {
      float4 m4 = *(const float4*)(mr + 4 * i);
      float4 s4 = *(const float4*)(sr + 4 * i);
      float4 x4 = *(const float4*)(&xr[qq * 64 + 4 * i]);
      { float is = 1.f / s4.x; float df = (x4.x - m4.x) * is; s2 += df * df; ls += __logf(s4.x); }
      { float is = 1.f / s4.y; float df = (x4.y - m4.y) * is; s2 += df * df; ls += __logf(s4.y); }
      { float is = 1.f / s4.z; float df = (x4.z - m4.z) * is; s2 += df * df; ls += __logf(s4.z); }
      { float is = 1.f / s4.w; float df = (x4.w - m4.w) * is; s2 += df * df; ls += __logf(s4.w); }
    }
    part[tid] = -0.5f * s2 - ls;
  }
  __syncthreads();

  if (tid < 64) {                      // exact top-32 + softmax (wave 0)
    float lp0 = part[l * 4] + part[l * 4 + 1] + part[l * 4 + 2] +
                part[l * 4 + 3] - LOG2PI_TERM;
    u32 ext = (fkey(lp0) & 0xFFFFFFC0u) | (u32)l;
    float maxlp = 0.f, ssum = 0.f;
    for (int it = 0; it < 32; ++it) {
      u32 m = ext;
      REDUCE_MAX(m)
      int j = (int)(m & 63u);
      u32 vb = m & 0xFFFFFFC0u;
      vb ^= (vb >> 31) ? 0x80000000u : 0xFFFFFFFFu;
      float lp = __uint_as_float(vb);
      if (it == 0) maxlp = lp;
      float e = __expf(lp - maxlp);
      ssum += e;
      if (l == 0) { ew[it] = e; kf[it] = selk[j]; }
      if (j == l) ext = 0;
    }
    if (l == 0) invs_sh = 1.0f / ssum;
  }
  __syncthreads();
#undef REDUCE_MAX

  {  // weighted gather: one output element per thread
    float a = 0.f;
    for (int i = 0; i < 32; ++i)
      a += ew[i] * outs[(size_t)kf[i] * ODIM + tid];
    out[(size_t)row * ODIM + tid] = a * invs_sh;
  }
}

// ---------------------------------------------------------------------------
extern "C" void kernel_launch(void* const* d_in, const int* in_sizes, int n_in,
                              void* d_out, int out_size, void* d_ws, size_t ws_size,
                              hipStream_t stream) {
  const float* x = (const float*)d_in[0];
  const float* mean = (const float*)d_in[1];
  const float* stdd = (const float*)d_in[2];
  const float* outs = (const float*)d_in[3];
  char* ws = (char*)d_ws;
  u16* A_ws = (u16*)(ws + WS_A);
  u32* ckey = (u32*)(ws + WS_KEY);

  prep_A<<<64, 256, 0, stream>>>(x, A_ws);
  main_gemm<<<NBLK, 256, 0, stream>>>(A_ws, mean, stdd, ckey);
  finalize<<<BROWS, 256, 0, stream>>>(x, mean, stdd, outs, ckey,
                                      (float*)d_out);
}